// Round 9
// baseline (870.346 us; speedup 1.0000x reference)
//
#include <hip/hip_runtime.h>
#include <hip/hip_bf16.h>
#include <stdint.h>

// Swin window attention, B=32, H=W=56, DIM=512, HEADS=16, HD=32, WS=7, shift=3.
// Round 9: k_prep_x fused into k_qkv — A-tile reg-staged straight from fp32 x
// (rolled rows via lutr), converted in-register, ds_written with bank-balanced
// XOR swizzle (chunk c -> c^(row&7), the involution the reads already use).
// Counted-vmcnt pipeline kept from R8 (vmcnt(12) = A8+B4 of tile t+1 in flight).

#define NWIN 64
#define NTOK 49
#define WIN_ELEMS 1568        // 49*32
#define HEAD_STRIDE 100352    // 64*49*32
#define BATCH_STRIDE 1605632  // 16*64*49*32
#define QKV_ELEMS 51380224    // 32*16*64*49*32
#define NTOKENS 100352
#define SCALE 0.17677669529663687f

typedef __attribute__((ext_vector_type(8))) short bf16x8;
typedef __attribute__((ext_vector_type(4))) float f32x4;

#define AS1 __attribute__((address_space(1)))
#define AS3 __attribute__((address_space(3)))

struct __align__(16) bf8 { __hip_bfloat16 h[8]; };

__device__ __forceinline__ void gload_lds16(const void* g, void* l) {
  __builtin_amdgcn_global_load_lds((const AS1 unsigned int*)g,
                                   (AS3 unsigned int*)l, 16, 0, 0);
}

__device__ __forceinline__ void token_decode(int t, int& b, int& i, int& j) {
  b = t / 3136;
  int r = t - b * 3136;
  i = r / 56;
  j = r - i * 56;
}

__device__ __forceinline__ bf8 pack8(const float4& a, const float4& b) {
  bf8 o;
  o.h[0] = __float2bfloat16(a.x); o.h[1] = __float2bfloat16(a.y);
  o.h[2] = __float2bfloat16(a.z); o.h[3] = __float2bfloat16(a.w);
  o.h[4] = __float2bfloat16(b.x); o.h[5] = __float2bfloat16(b.y);
  o.h[6] = __float2bfloat16(b.z); o.h[7] = __float2bfloat16(b.w);
  return o;
}

// ---------------- P0: token offset LUTs ----------------
// lutr: rolled x row offset (fp32 elems); lutw: windowed qkv; luto: rolled out.
__global__ __launch_bounds__(256) void k_prep_lut(int* __restrict__ lutr,
                                                  int* __restrict__ lutw,
                                                  int* __restrict__ luto) {
  int t = blockIdx.x * 256 + threadIdx.x;       // 392 blocks
  int b, i, j;
  token_decode(t, b, i, j);
  int si = i + 3; if (si >= 56) si -= 56;
  int sj = j + 3; if (sj >= 56) sj -= 56;
  lutr[t] = ((b * 56 + si) * 56 + sj) * 512;
  int win = (i / 7) * 8 + (j / 7);
  int pos = (i % 7) * 7 + (j % 7);
  lutw[t] = b * BATCH_STRIDE + win * WIN_ELEMS + pos * 32;
  luto[t] = lutr[t];                            // roll(+3,+3) == roll(-3,-3) offsets
}

// ---------------- P2/P3: fp32 [K][N] -> bf16 [N][K] transpose, SWIZZLED ----------------
__global__ __launch_bounds__(256) void k_transpose(const float* __restrict__ in,
                                                   __hip_bfloat16* __restrict__ out,
                                                   int K, int N) {
  __shared__ float tl[64][65];
  const int nb = blockIdx.x * 64, kb = blockIdx.y * 64;
  const int tid = threadIdx.x;
#pragma unroll
  for (int s = 0; s < 16; ++s) {
    int idx = s * 256 + tid; int r = idx >> 6, c = idx & 63;
    tl[r][c] = in[(size_t)(kb + r) * N + nb + c];
  }
  __syncthreads();
#pragma unroll
  for (int s = 0; s < 16; ++s) {
    int idx = s * 256 + tid; int r = idx >> 6, c = idx & 63;
    int row = nb + r;
    int col = (kb + c) ^ ((row & 7) << 3);
    out[(size_t)row * K + col] = __float2bfloat16(tl[c][r]);
  }
}

// ---------------- P4: bias table in MFMA fragment layout ----------------
__global__ __launch_bounds__(256) void k_prep_bias(const float* __restrict__ pe,
                                                   float* __restrict__ biasT) {
  int id = blockIdx.x * 256 + threadIdx.x;      // 262144 total
  int whid = id >> 12;
  int wtype = whid >> 4, h = whid & 15;
  int mid = id & 4095;
  int mf = mid >> 10, r = (mid >> 8) & 3, lane = (mid >> 2) & 63, nf = mid & 3;
  int key = mf * 16 + (lane >> 4) * 4 + r;
  int query = nf * 16 + (lane & 15);
  float v;
  if (key >= 49 || query >= 49) {
    v = -1e30f;
  } else {
    int i = query, j = key;
    int xi = i / 7, yi = i - xi * 7;
    int xj = j / 7, yj = j - xj * 7;
    int dx = xj - xi; if (dx < 0) dx += 13;
    int dy = yj - yi; if (dy < 0) dy += 13;
    v = pe[(dx * 13 + dy) * 16 + h];
    if ((wtype & 1) && ((xi >= 4) != (xj >= 4))) v = -1e30f;
    if ((wtype & 2) && ((yi >= 4) != (yj >= 4))) v = -1e30f;
  }
  biasT[id] = v;
}

// ---------------- K1: QKV GEMM, bf16 MFMA, fused x-convert + counted-vmcnt ----------------
// M=100352, N=1536, K=512. 128x128 tile, BK=64, 4 waves (2x2), 64x64 per wave.
// A: fp32 x -> regs (8 float4/thread) -> bf16 -> swizzled ds_write into buf^1.
// B: gload_lds (producer-swizzled wbt). vmcnt(12) keeps tile t+1 in flight.
__global__ __launch_bounds__(256) void k_qkv_mfma(
    const float* __restrict__ x, const __hip_bfloat16* __restrict__ wbt,
    const int* __restrict__ lutr, const int* __restrict__ lutw,
    __hip_bfloat16* __restrict__ qb, __hip_bfloat16* __restrict__ kb,
    __hip_bfloat16* __restrict__ vb) {
  __shared__ __align__(16) short As[2][128 * 64];
  __shared__ __align__(16) short Bs[2][128 * 64];
  const int tid = threadIdx.x;
  const int lid = blockIdx.x;                 // 9408 blocks
  const int wid = (lid & 7) * 1176 + (lid >> 3);
  const int t0 = (wid / 12) * 128;
  const int n0 = (wid % 12) * 128;
  const int lane = tid & 63, wave = tid >> 6;
  const int wm = wave >> 1, wn = wave & 1;

  // A staging: thread covers row tid>>1, half (tid&1) of 64 cols (32 fp32).
  const int arow_s = tid >> 1, half = tid & 1;
  const float* axp = x + (size_t)lutr[t0 + arow_s] + half * 32;
  short* aw[2] = { &As[0][arow_s * 64], &As[1][arow_s * 64] };
  int wch[4];
#pragma unroll
  for (int c = 0; c < 4; ++c)
    wch[c] = ((half * 4 + c) ^ (arow_s & 7)) * 8;   // bank-balanced swizzle

  // B staging: gload_lds chunks (wbt producer-swizzled)
  const __hip_bfloat16* bsrc[4];
#pragma unroll
  for (int s = 0; s < 4; ++s) {
    int c = s * 256 + tid;
    int row = c >> 3, kc = c & 7;
    bsrc[s] = wbt + (size_t)(n0 + row) * 512 + kc * 8;
  }

  f32x4 acc[4][4] = {};
  const int arow = wm * 64 + (lane & 15);
  const int brow = wn * 64 + (lane & 15);
  const int koff = (lane >> 4) * 8;
  const int sw = (lane & 7) << 3;          // row&7 == lane&7 for all fragments

  float4 ar[8];
  // prologue: tile 0 — A to regs->LDS buf0, B gload buf0
#pragma unroll
  for (int u = 0; u < 8; ++u) ar[u] = ((const float4*)axp)[u];
#pragma unroll
  for (int s = 0; s < 4; ++s)
    gload_lds16(bsrc[s], (char*)Bs[0] + wave * 1024 + s * 4096);
#pragma unroll
  for (int c = 0; c < 4; ++c)
    *(bf8*)(aw[0] + wch[c]) = pack8(ar[2 * c], ar[2 * c + 1]);
  asm volatile("s_waitcnt lgkmcnt(0)" ::: "memory");

  for (int t = 0; t < 8; ++t) {
    const int buf = t & 1;
    if (t < 7) {
      const int kt = (t + 1) * 64;
      const float* p = axp + kt;
#pragma unroll
      for (int u = 0; u < 8; ++u) ar[u] = ((const float4*)p)[u];
#pragma unroll
      for (int s = 0; s < 4; ++s)
        gload_lds16(bsrc[s] + kt, (char*)Bs[buf ^ 1] + wave * 1024 + s * 4096);
      asm volatile("s_waitcnt vmcnt(12)" ::: "memory");  // drain B(t); t+1 in flight
    } else {
      asm volatile("s_waitcnt vmcnt(0)" ::: "memory");
    }
    __builtin_amdgcn_s_barrier();            // raw: no implicit drain
    __builtin_amdgcn_sched_barrier(0);

    bf16x8 af[2][4], bfr[2][4];
#pragma unroll
    for (int kk = 0; kk < 2; ++kk) {
      const int eo = (kk * 32 + koff) ^ sw;
#pragma unroll
      for (int mf = 0; mf < 4; ++mf)
        af[kk][mf] = *(const bf16x8*)&As[buf][(arow + mf * 16) * 64 + eo];
#pragma unroll
      for (int nf = 0; nf < 4; ++nf)
        bfr[kk][nf] = *(const bf16x8*)&Bs[buf][(brow + nf * 16) * 64 + eo];
    }
    __builtin_amdgcn_s_setprio(1);
#pragma unroll
    for (int kk = 0; kk < 2; ++kk)
#pragma unroll
      for (int mf = 0; mf < 4; ++mf)
#pragma unroll
        for (int nf = 0; nf < 4; ++nf)
          acc[mf][nf] = __builtin_amdgcn_mfma_f32_16x16x32_bf16(
              af[kk][mf], bfr[kk][nf], acc[mf][nf], 0, 0, 0);
    __builtin_amdgcn_s_setprio(0);
    if (t < 7) {                             // convert+write A(t+1) into buf^1
#pragma unroll
      for (int c = 0; c < 4; ++c)
        *(bf8*)(aw[buf ^ 1] + wch[c]) = pack8(ar[2 * c], ar[2 * c + 1]);
    }
    asm volatile("s_waitcnt lgkmcnt(0)" ::: "memory");   // writes visible pre-barrier
    __builtin_amdgcn_s_barrier();
    __builtin_amdgcn_sched_barrier(0);
  }

  // epilogue: q/k/v -> windowed [b][h][win][pos49][d32]; offsets via LUT
  __hip_bfloat16* obs[4];
#pragma unroll
  for (int nf = 0; nf < 4; ++nf) {
    int n = n0 + wn * 64 + nf * 16 + (lane & 15);
    int sp = n >> 9, hc = n & 511, h = hc >> 5, d = hc & 31;
    obs[nf] = (sp == 0 ? qb : (sp == 1 ? kb : vb)) + (size_t)h * HEAD_STRIDE + d;
  }
  const int tbase = t0 + wm * 64 + (lane >> 4) * 4;
  int woff[4][4];
#pragma unroll
  for (int mf = 0; mf < 4; ++mf)
#pragma unroll
    for (int r = 0; r < 4; ++r)
      woff[mf][r] = lutw[tbase + mf * 16 + r];
#pragma unroll
  for (int mf = 0; mf < 4; ++mf)
#pragma unroll
    for (int r = 0; r < 4; ++r) {
      size_t off = (size_t)woff[mf][r];
#pragma unroll
      for (int nf = 0; nf < 4; ++nf)
        obs[nf][off] = __float2bfloat16(acc[mf][nf][r]);
    }
}

// ---------------- K2: attention via MFMA, one wave per (b,h,win) ----------------
__global__ __launch_bounds__(256) void k_attn_mfma(
    const __hip_bfloat16* __restrict__ qb, const __hip_bfloat16* __restrict__ kb,
    const __hip_bfloat16* __restrict__ vb, const float* __restrict__ biasT,
    __hip_bfloat16* __restrict__ ab) {
  __shared__ __align__(16) __hip_bfloat16 P[4][64 * 72];   // per-wave P[query][key]
  __shared__ __align__(16) __hip_bfloat16 VT[4][32 * 64];  // per-wave V^T[d][pos^swz]
  const int tid = threadIdx.x, lane = tid & 63, wave = tid >> 6;
  const int gid = blockIdx.x * 4 + wave;                   // (b*16+h)*64 + win
  const int win = gid & 63, h = (gid >> 6) & 15;
  const int wtype = (((win >> 3) == 7) ? 1 : 0) | (((win & 7) == 7) ? 2 : 0);
  const size_t qkbase = (size_t)gid * WIN_ELEMS;
  const int fr = lane & 15, fo = (lane >> 4) * 8;

  // issue V loads early (196 bf8 chunks over 64 lanes, 4 iters)
  bf8 v8[4];
#pragma unroll
  for (int it = 0; it < 4; ++it) {
    int c = it * 64 + lane;
    if (c < 196) v8[it] = *(const bf8*)(vb + qkbase + (size_t)c * 8);
  }

  // Q,K fragments straight from global ([tok][d32], d==K of MFMA)
  bf16x8 kf[4], qf[4];
#pragma unroll
  for (int f = 0; f < 4; ++f) {
    kf[f] = *(const bf16x8*)(kb + qkbase + (size_t)(f * 16 + fr) * 32 + fo);
    qf[f] = *(const bf16x8*)(qb + qkbase + (size_t)(f * 16 + fr) * 32 + fo);
  }

  // zero VT (pads pos 49..63 and unwritten rows), then transpose V into it
  __hip_bfloat16* vtw = VT[wave];
  {
    bf16x8 zz = {};
#pragma unroll
    for (int z = 0; z < 4; ++z) *(bf16x8*)&vtw[z * 512 + lane * 8] = zz;
  }
#pragma unroll
  for (int it = 0; it < 4; ++it) {
    int c = it * 64 + lane;
    if (c < 196) {
      int pos = c >> 2, d0 = (c & 3) * 8;
#pragma unroll
      for (int u = 0; u < 8; ++u) {
        int d = d0 + u;
        vtw[d * 64 + (pos ^ ((d & 7) << 3))] = v8[it].h[u];
      }
    }
  }

  // S^T[key][query] = K @ Q^T
  f32x4 sacc[4][4] = {};   // [key-frag mf][query-frag nf]
#pragma unroll
  for (int mf = 0; mf < 4; ++mf)
#pragma unroll
    for (int nf = 0; nf < 4; ++nf)
      sacc[mf][nf] = __builtin_amdgcn_mfma_f32_16x16x32_bf16(
          kf[mf], qf[nf], sacc[mf][nf], 0, 0, 0);

  // scale + bias/mask table (fragment-layout, coalesced float4)
  const float* bp = biasT + (size_t)(wtype * 16 + h) * 4096;
#pragma unroll
  for (int mf = 0; mf < 4; ++mf)
#pragma unroll
    for (int r = 0; r < 4; ++r) {
      float4 bv = *(const float4*)(bp + ((mf * 4 + r) * 64 + lane) * 4);
      sacc[mf][0][r] = fmaf(sacc[mf][0][r], SCALE, bv.x);
      sacc[mf][1][r] = fmaf(sacc[mf][1][r], SCALE, bv.y);
      sacc[mf][2][r] = fmaf(sacc[mf][2][r], SCALE, bv.z);
      sacc[mf][3][r] = fmaf(sacc[mf][3][r], SCALE, bv.w);
    }

  // softmax over keys (rows of S^T): per query col, 16 local + 2 shuffles
  float inv[4];
#pragma unroll
  for (int nf = 0; nf < 4; ++nf) {
    float m = sacc[0][nf][0];
#pragma unroll
    for (int mf = 0; mf < 4; ++mf)
#pragma unroll
      for (int r = 0; r < 4; ++r) m = fmaxf(m, sacc[mf][nf][r]);
    m = fmaxf(m, __shfl_xor(m, 16));
    m = fmaxf(m, __shfl_xor(m, 32));
    float sum = 0.f;
#pragma unroll
    for (int mf = 0; mf < 4; ++mf)
#pragma unroll
      for (int r = 0; r < 4; ++r) {
        float e = __expf(sacc[mf][nf][r] - m);
        sacc[mf][nf][r] = e;
        sum += e;
      }
    sum += __shfl_xor(sum, 16);
    sum += __shfl_xor(sum, 32);
    inv[nf] = 1.0f / sum;
  }

  // write P[query][key] (bf16) to LDS, transposed back for PV A-operand
  __hip_bfloat16* pw = P[wave];
#pragma unroll
  for (int mf = 0; mf < 4; ++mf)
#pragma unroll
    for (int r = 0; r < 4; ++r) {
      int key = mf * 16 + (lane >> 4) * 4 + r;
#pragma unroll
      for (int nf = 0; nf < 4; ++nf) {
        int query = nf * 16 + fr;
        pw[query * 72 + key] = __float2bfloat16(sacc[mf][nf][r] * inv[nf]);
      }
    }

  // O = P @ V via MFMA; V^T from per-wave LDS (XOR-swizzled pos)
  f32x4 oacc[4][2] = {};
#pragma unroll
  for (int kk = 0; kk < 2; ++kk) {
    bf16x8 vf[2];
#pragma unroll
    for (int n2 = 0; n2 < 2; ++n2) {
      int d = n2 * 16 + fr;
      vf[n2] = *(const bf16x8*)&vtw[d * 64 + ((kk * 32 + fo) ^ ((d & 7) << 3))];
    }
#pragma unroll
    for (int mf = 0; mf < 4; ++mf) {
      bf16x8 pa = *(const bf16x8*)&pw[(mf * 16 + fr) * 72 + kk * 32 + fo];
#pragma unroll
      for (int n2 = 0; n2 < 2; ++n2)
        oacc[mf][n2] = __builtin_amdgcn_mfma_f32_16x16x32_bf16(
            pa, vf[n2], oacc[mf][n2], 0, 0, 0);
    }
  }

  // store O rows < 49 to windowed [tok49][d32]
#pragma unroll
  for (int mf = 0; mf < 4; ++mf)
#pragma unroll
    for (int r = 0; r < 4; ++r) {
      int row = mf * 16 + (lane >> 4) * 4 + r;
      if (row < 49) {
#pragma unroll
        for (int n2 = 0; n2 < 2; ++n2)
          ab[qkbase + (size_t)row * 32 + n2 * 16 + fr] =
              __float2bfloat16(oacc[mf][n2][r]);
      }
    }
}

// ---------------- K3: output GEMM, bf16 MFMA, counted-vmcnt pipeline ----------------
// M=100352, N=512, K=512. B (wot) swizzled; A (ab) linear.
__global__ __launch_bounds__(256) void k_out_mfma(
    const __hip_bfloat16* __restrict__ ab, const __hip_bfloat16* __restrict__ wot,
    const int* __restrict__ lutw, const int* __restrict__ luto,
    const float* __restrict__ bias, float* __restrict__ out) {
  __shared__ __align__(16) short As[2][128 * 64];
  __shared__ __align__(16) short Bs[2][128 * 64];
  const int tid = threadIdx.x;
  const int lid = blockIdx.x;                 // 3136 blocks
  const int wid = (lid & 7) * 392 + (lid >> 3);
  const int t0 = (wid >> 2) * 128;
  const int n0 = (wid & 3) * 128;
  const int lane = tid & 63, wave = tid >> 6;
  const int wm = wave >> 1, wn = wave & 1;

  size_t aoff[4];
  const __hip_bfloat16* bsrc[4];
#pragma unroll
  for (int s = 0; s < 4; ++s) {
    int c = s * 256 + tid;
    int row = c >> 3, kc = c & 7;
    aoff[s] = (size_t)lutw[t0 + row] + (size_t)(kc >> 2) * HEAD_STRIDE + (kc & 3) * 8;
    bsrc[s] = wot + (size_t)(n0 + row) * 512 + kc * 8;
  }

  f32x4 acc[4][4] = {};
  const int arow = wm * 64 + (lane & 15);
  const int brow = wn * 64 + (lane & 15);
  const int koff = (lane >> 4) * 8;
  const int sw = (lane & 7) << 3;

  // prologue: stage K-tile 0 into buf 0
#pragma unroll
  for (int s = 0; s < 4; ++s) {
    gload_lds16(ab + aoff[s], (char*)As[0] + wave * 1024 + s * 4096);
    gload_lds16(bsrc[s], (char*)Bs[0] + wave * 1024 + s * 4096);
  }

  for (int t = 0; t < 8; ++t) {
    const int buf = t & 1;
    if (t < 7) {
      const int kt = (t + 1) * 64;
      size_t hoff = (size_t)(kt >> 5) * HEAD_STRIDE;
#pragma unroll
      for (int s = 0; s < 4; ++s) {
        gload_lds16(ab + aoff[s] + hoff, (char*)As[buf ^ 1] + wave * 1024 + s * 4096);
        gload_lds16(bsrc[s] + kt, (char*)Bs[buf ^ 1] + wave * 1024 + s * 4096);
      }
      asm volatile("s_waitcnt vmcnt(8)" ::: "memory");
    } else {
      asm volatile("s_waitcnt vmcnt(0)" ::: "memory");
    }
    __builtin_amdgcn_s_barrier();
    __builtin_amdgcn_sched_barrier(0);

    bf16x8 af[2][4], bfr[2][4];
#pragma unroll
    for (int kk = 0; kk < 2; ++kk) {
      const int eo = kk * 32 + koff;
#pragma unroll
      for (int mf = 0; mf < 4; ++mf)
        af[kk][mf] = *(const bf16x8*)&As[buf][(arow + mf * 16) * 64 + eo];
#pragma unroll
      for (int nf = 0; nf < 4; ++nf)
        bfr[kk][nf] = *(const bf16x8*)&Bs[buf][(brow + nf * 16) * 64 + (eo ^ sw)];
    }
    __builtin_amdgcn_s_setprio(1);
#pragma unroll
    for (int kk = 0; kk < 2; ++kk)
#pragma unroll
      for (int mf = 0; mf < 4; ++mf)
#pragma unroll
        for (int nf = 0; nf < 4; ++nf)
          acc[mf][nf] = __builtin_amdgcn_mfma_f32_16x16x32_bf16(
              af[kk][mf], bfr[kk][nf], acc[mf][nf], 0, 0, 0);
    __builtin_amdgcn_s_setprio(0);
    __builtin_amdgcn_s_barrier();
    __builtin_amdgcn_sched_barrier(0);
  }

  float bia[4];
#pragma unroll
  for (int nf = 0; nf < 4; ++nf)
    bia[nf] = bias[n0 + wn * 64 + nf * 16 + (lane & 15)];

  const int tbase = t0 + wm * 64 + (lane >> 4) * 4;
  int ooff[4][4];
#pragma unroll
  for (int mf = 0; mf < 4; ++mf)
#pragma unroll
    for (int r = 0; r < 4; ++r)
      ooff[mf][r] = luto[tbase + mf * 16 + r];
#pragma unroll
  for (int mf = 0; mf < 4; ++mf) {
#pragma unroll
    for (int r = 0; r < 4; ++r) {
      float* op = out + (size_t)ooff[mf][r] + n0 + wn * 64 + (lane & 15);
#pragma unroll
      for (int nf = 0; nf < 4; ++nf) op[nf * 16] = acc[mf][nf][r] + bia[nf];
    }
  }
}

extern "C" void kernel_launch(void* const* d_in, const int* in_sizes, int n_in,
                              void* d_out, int out_size, void* d_ws, size_t ws_size,
                              hipStream_t stream) {
  const float* x     = (const float*)d_in[0];
  const float* w_qkv = (const float*)d_in[1];
  const float* pe    = (const float*)d_in[2];
  const float* w_out = (const float*)d_in[3];
  const float* b_out = (const float*)d_in[4];
  float* out = (float*)d_out;

  __hip_bfloat16* qb  = (__hip_bfloat16*)d_ws;          // 51,380,224
  __hip_bfloat16* kb  = qb + (size_t)QKV_ELEMS;         // 51,380,224
  __hip_bfloat16* vb  = kb + (size_t)QKV_ELEMS;         // 51,380,224
  __hip_bfloat16* ab  = vb + (size_t)QKV_ELEMS;         // 51,380,224
  __hip_bfloat16* wbt = ab + (size_t)QKV_ELEMS;         // 786,432
  __hip_bfloat16* wot = wbt + (size_t)(1536 * 512);     // 262,144
  float* biasT = (float*)(wot + (size_t)(512 * 512));   // 262,144 f32 (1 MB)
  int* lutr = (int*)(biasT + 262144);                   // 100,352 int
  int* lutw = lutr + NTOKENS;                           // 100,352 int
  int* luto = lutw + NTOKENS;                           // 100,352 int

  k_prep_lut<<<dim3(392), dim3(256), 0, stream>>>(lutr, lutw, luto);
  k_transpose<<<dim3(24, 8), dim3(256), 0, stream>>>(w_qkv, wbt, 512, 1536);
  k_transpose<<<dim3(8, 8), dim3(256), 0, stream>>>(w_out, wot, 512, 512);
  k_prep_bias<<<dim3(1024), dim3(256), 0, stream>>>(pe, biasT);
  k_qkv_mfma<<<dim3(9408), dim3(256), 0, stream>>>(x, wbt, lutr, lutw, qb, kb, vb);
  k_attn_mfma<<<dim3(8192), dim3(256), 0, stream>>>(qb, kb, vb, biasT, ab);
  k_out_mfma<<<dim3(3136), dim3(256), 0, stream>>>(ab, wot, lutw, luto, b_out, out);
}

// Round 10
// 629.166 us; speedup vs baseline: 1.3833x; 1.3833x over previous
//
#include <hip/hip_runtime.h>
#include <hip/hip_bf16.h>
#include <stdint.h>

// Swin window attention, B=32, H=W=56, DIM=512, HEADS=16, HD=32, WS=7, shift=3.
// Round 10: revert R9 fusion (dead end). R8 base + k_qkv restructured to
// 256x128 block / 128x64 wave tile (acc[8][4]) to cut LDS bytes per FLOP by
// ~1.35x (LDS pipe was ~54% busy = largest pipe). Single-buffer 48KB LDS,
// 2-phase __syncthreads. k_prep_x re-gridded (128B/thread). k_out/k_attn = R8.

#define NWIN 64
#define NTOK 49
#define WIN_ELEMS 1568        // 49*32
#define HEAD_STRIDE 100352    // 64*49*32
#define BATCH_STRIDE 1605632  // 16*64*49*32
#define QKV_ELEMS 51380224    // 32*16*64*49*32
#define NTOKENS 100352
#define SCALE 0.17677669529663687f

typedef __attribute__((ext_vector_type(8))) short bf16x8;
typedef __attribute__((ext_vector_type(4))) float f32x4;

#define AS1 __attribute__((address_space(1)))
#define AS3 __attribute__((address_space(3)))

struct __align__(16) bf8 { __hip_bfloat16 h[8]; };

__device__ __forceinline__ void gload_lds16(const void* g, void* l) {
  __builtin_amdgcn_global_load_lds((const AS1 unsigned int*)g,
                                   (AS3 unsigned int*)l, 16, 0, 0);
}

__device__ __forceinline__ void token_decode(int t, int& b, int& i, int& j) {
  b = t / 3136;
  int r = t - b * 3136;
  i = r / 56;
  j = r - i * 56;
}

// ---------------- P0: token offset LUTs ----------------
__global__ __launch_bounds__(256) void k_prep_lut(int* __restrict__ lutw,
                                                  int* __restrict__ luto) {
  int t = blockIdx.x * 256 + threadIdx.x;       // 392 blocks
  int b, i, j;
  token_decode(t, b, i, j);
  int win = (i / 7) * 8 + (j / 7);
  int pos = (i % 7) * 7 + (j % 7);
  lutw[t] = b * BATCH_STRIDE + win * WIN_ELEMS + pos * 32;
  int di = i + 3; if (di >= 56) di -= 56;
  int dj = j + 3; if (dj >= 56) dj -= 56;
  luto[t] = ((b * 56 + di) * 56 + dj) * 512;
}

// ---------------- P1: x -> bf16, roll(-3,-3), SWIZZLED slot store ----------------
// 6272 blocks; thread handles 32 elems (128B read) of one row.
__global__ __launch_bounds__(256) void k_prep_x(const float* __restrict__ x,
                                                __hip_bfloat16* __restrict__ xb) {
  int idx = blockIdx.x * 256 + threadIdx.x;
  int t = idx >> 4;
  int q = idx & 15;                       // quarter-row segment: chunks 4q..4q+3
  int b, i, j;
  token_decode(t, b, i, j);
  int si = i + 3; if (si >= 56) si -= 56;
  int sj = j + 3; if (sj >= 56) sj -= 56;
  const float* src = x + ((size_t)(b * 56 + si) * 56 + sj) * 512 + q * 32;
  __hip_bfloat16* dst = xb + (size_t)t * 512;
  const int rsw = t & 7;
#pragma unroll
  for (int c = 0; c < 4; ++c) {
    float4 a0 = *(const float4*)(src + c * 8);
    float4 a1 = *(const float4*)(src + c * 8 + 4);
    bf8 o;
    o.h[0] = __float2bfloat16(a0.x); o.h[1] = __float2bfloat16(a0.y);
    o.h[2] = __float2bfloat16(a0.z); o.h[3] = __float2bfloat16(a0.w);
    o.h[4] = __float2bfloat16(a1.x); o.h[5] = __float2bfloat16(a1.y);
    o.h[6] = __float2bfloat16(a1.z); o.h[7] = __float2bfloat16(a1.w);
    int g = q * 4 + c;
    *(bf8*)(dst + ((g ^ rsw) << 3)) = o;
  }
}

// ---------------- P2/P3: fp32 [K][N] -> bf16 [N][K] transpose, SWIZZLED ----------------
__global__ __launch_bounds__(256) void k_transpose(const float* __restrict__ in,
                                                   __hip_bfloat16* __restrict__ out,
                                                   int K, int N) {
  __shared__ float tl[64][65];
  const int nb = blockIdx.x * 64, kb = blockIdx.y * 64;
  const int tid = threadIdx.x;
#pragma unroll
  for (int s = 0; s < 16; ++s) {
    int idx = s * 256 + tid; int r = idx >> 6, c = idx & 63;
    tl[r][c] = in[(size_t)(kb + r) * N + nb + c];
  }
  __syncthreads();
#pragma unroll
  for (int s = 0; s < 16; ++s) {
    int idx = s * 256 + tid; int r = idx >> 6, c = idx & 63;
    int row = nb + r;
    int col = (kb + c) ^ ((row & 7) << 3);
    out[(size_t)row * K + col] = __float2bfloat16(tl[c][r]);
  }
}

// ---------------- P4: bias table in MFMA fragment layout ----------------
__global__ __launch_bounds__(256) void k_prep_bias(const float* __restrict__ pe,
                                                   float* __restrict__ biasT) {
  int id = blockIdx.x * 256 + threadIdx.x;      // 262144 total
  int whid = id >> 12;
  int wtype = whid >> 4, h = whid & 15;
  int mid = id & 4095;
  int mf = mid >> 10, r = (mid >> 8) & 3, lane = (mid >> 2) & 63, nf = mid & 3;
  int key = mf * 16 + (lane >> 4) * 4 + r;
  int query = nf * 16 + (lane & 15);
  float v;
  if (key >= 49 || query >= 49) {
    v = -1e30f;
  } else {
    int i = query, j = key;
    int xi = i / 7, yi = i - xi * 7;
    int xj = j / 7, yj = j - xj * 7;
    int dx = xj - xi; if (dx < 0) dx += 13;
    int dy = yj - yi; if (dy < 0) dy += 13;
    v = pe[(dx * 13 + dy) * 16 + h];
    if ((wtype & 1) && ((xi >= 4) != (xj >= 4))) v = -1e30f;
    if ((wtype & 2) && ((yi >= 4) != (yj >= 4))) v = -1e30f;
  }
  biasT[id] = v;
}

// ---------------- K1: QKV GEMM, bf16 MFMA, 256x128 block / 128x64 wave ----------------
// M=100352, N=1536, K=512. 4704 blocks, 4 waves (2Mx2N), acc[8][4]/wave.
// Single-buffer 48KB LDS, 2-phase sync. Producer-swizzled xb/wbt (conflict-free).
__global__ __launch_bounds__(256) void k_qkv_mfma(
    const __hip_bfloat16* __restrict__ xb, const __hip_bfloat16* __restrict__ wbt,
    const int* __restrict__ lutw,
    __hip_bfloat16* __restrict__ qb, __hip_bfloat16* __restrict__ kb,
    __hip_bfloat16* __restrict__ vb) {
  __shared__ __align__(16) short As[256 * 64];   // 32 KB
  __shared__ __align__(16) short Bs[128 * 64];   // 16 KB
  const int tid = threadIdx.x;
  const int lid = blockIdx.x;                 // 4704 blocks
  const int wid = (lid & 7) * 588 + (lid >> 3);
  const int t0 = (wid / 12) * 256;
  const int n0 = (wid % 12) * 128;
  const int lane = tid & 63, wave = tid >> 6;
  const int wm = wave >> 1, wn = wave & 1;

  const __hip_bfloat16* asrc[8];
#pragma unroll
  for (int s = 0; s < 8; ++s) {
    int c = s * 256 + tid;
    int row = c >> 3, kc = c & 7;
    asrc[s] = xb + (size_t)(t0 + row) * 512 + kc * 8;
  }
  const __hip_bfloat16* bsrc[4];
#pragma unroll
  for (int s = 0; s < 4; ++s) {
    int c = s * 256 + tid;
    int row = c >> 3, kc = c & 7;
    bsrc[s] = wbt + (size_t)(n0 + row) * 512 + kc * 8;
  }

  f32x4 acc[8][4] = {};
  const int arow = wm * 128 + (lane & 15);
  const int brow = wn * 64 + (lane & 15);
  const int koff = (lane >> 4) * 8;
  const int sw = (lane & 7) << 3;          // row&7 == lane&7 for all fragments

  for (int kt = 0; kt < 512; kt += 64) {
#pragma unroll
    for (int s = 0; s < 8; ++s)
      gload_lds16(asrc[s] + kt, (char*)As + s * 4096 + wave * 1024);
#pragma unroll
    for (int s = 0; s < 4; ++s)
      gload_lds16(bsrc[s] + kt, (char*)Bs + s * 4096 + wave * 1024);
    __syncthreads();                        // drains vmcnt: tiles resident
#pragma unroll
    for (int kk = 0; kk < 2; ++kk) {
      const int eo = (kk * 32 + koff) ^ sw;
      bf16x8 af[8], bfr[4];
#pragma unroll
      for (int nf = 0; nf < 4; ++nf)
        bfr[nf] = *(const bf16x8*)&Bs[(brow + nf * 16) * 64 + eo];
#pragma unroll
      for (int mf = 0; mf < 8; ++mf)
        af[mf] = *(const bf16x8*)&As[(arow + mf * 16) * 64 + eo];
#pragma unroll
      for (int mf = 0; mf < 8; ++mf)
#pragma unroll
        for (int nf = 0; nf < 4; ++nf)
          acc[mf][nf] = __builtin_amdgcn_mfma_f32_16x16x32_bf16(
              af[mf], bfr[nf], acc[mf][nf], 0, 0, 0);
    }
    __syncthreads();
  }

  // epilogue: q/k/v -> windowed [b][h][win][pos49][d32]; offsets via LUT
  __hip_bfloat16* obs[4];
#pragma unroll
  for (int nf = 0; nf < 4; ++nf) {
    int n = n0 + wn * 64 + nf * 16 + (lane & 15);
    int sp = n >> 9, hc = n & 511, h = hc >> 5, d = hc & 31;
    obs[nf] = (sp == 0 ? qb : (sp == 1 ? kb : vb)) + (size_t)h * HEAD_STRIDE + d;
  }
  const int tbase = t0 + wm * 128 + (lane >> 4) * 4;
#pragma unroll
  for (int mf = 0; mf < 8; ++mf) {
#pragma unroll
    for (int r = 0; r < 4; ++r) {
      size_t off = (size_t)lutw[tbase + mf * 16 + r];
#pragma unroll
      for (int nf = 0; nf < 4; ++nf)
        obs[nf][off] = __float2bfloat16(acc[mf][nf][r]);
    }
  }
}

// ---------------- K2: attention via MFMA, one wave per (b,h,win) ----------------
__global__ __launch_bounds__(256) void k_attn_mfma(
    const __hip_bfloat16* __restrict__ qb, const __hip_bfloat16* __restrict__ kb,
    const __hip_bfloat16* __restrict__ vb, const float* __restrict__ biasT,
    __hip_bfloat16* __restrict__ ab) {
  __shared__ __align__(16) __hip_bfloat16 P[4][64 * 72];   // per-wave P[query][key]
  __shared__ __align__(16) __hip_bfloat16 VT[4][32 * 64];  // per-wave V^T[d][pos^swz]
  const int tid = threadIdx.x, lane = tid & 63, wave = tid >> 6;
  const int gid = blockIdx.x * 4 + wave;                   // (b*16+h)*64 + win
  const int win = gid & 63, h = (gid >> 6) & 15;
  const int wtype = (((win >> 3) == 7) ? 1 : 0) | (((win & 7) == 7) ? 2 : 0);
  const size_t qkbase = (size_t)gid * WIN_ELEMS;
  const int fr = lane & 15, fo = (lane >> 4) * 8;

  // issue V loads early (196 bf8 chunks over 64 lanes, 4 iters)
  bf8 v8[4];
#pragma unroll
  for (int it = 0; it < 4; ++it) {
    int c = it * 64 + lane;
    if (c < 196) v8[it] = *(const bf8*)(vb + qkbase + (size_t)c * 8);
  }

  // Q,K fragments straight from global ([tok][d32], d==K of MFMA)
  bf16x8 kf[4], qf[4];
#pragma unroll
  for (int f = 0; f < 4; ++f) {
    kf[f] = *(const bf16x8*)(kb + qkbase + (size_t)(f * 16 + fr) * 32 + fo);
    qf[f] = *(const bf16x8*)(qb + qkbase + (size_t)(f * 16 + fr) * 32 + fo);
  }

  // zero VT (pads pos 49..63 and unwritten rows), then transpose V into it
  __hip_bfloat16* vtw = VT[wave];
  {
    bf16x8 zz = {};
#pragma unroll
    for (int z = 0; z < 4; ++z) *(bf16x8*)&vtw[z * 512 + lane * 8] = zz;
  }
#pragma unroll
  for (int it = 0; it < 4; ++it) {
    int c = it * 64 + lane;
    if (c < 196) {
      int pos = c >> 2, d0 = (c & 3) * 8;
#pragma unroll
      for (int u = 0; u < 8; ++u) {
        int d = d0 + u;
        vtw[d * 64 + (pos ^ ((d & 7) << 3))] = v8[it].h[u];
      }
    }
  }

  // S^T[key][query] = K @ Q^T
  f32x4 sacc[4][4] = {};   // [key-frag mf][query-frag nf]
#pragma unroll
  for (int mf = 0; mf < 4; ++mf)
#pragma unroll
    for (int nf = 0; nf < 4; ++nf)
      sacc[mf][nf] = __builtin_amdgcn_mfma_f32_16x16x32_bf16(
          kf[mf], qf[nf], sacc[mf][nf], 0, 0, 0);

  // scale + bias/mask table (fragment-layout, coalesced float4)
  const float* bp = biasT + (size_t)(wtype * 16 + h) * 4096;
#pragma unroll
  for (int mf = 0; mf < 4; ++mf)
#pragma unroll
    for (int r = 0; r < 4; ++r) {
      float4 bv = *(const float4*)(bp + ((mf * 4 + r) * 64 + lane) * 4);
      sacc[mf][0][r] = fmaf(sacc[mf][0][r], SCALE, bv.x);
      sacc[mf][1][r] = fmaf(sacc[mf][1][r], SCALE, bv.y);
      sacc[mf][2][r] = fmaf(sacc[mf][2][r], SCALE, bv.z);
      sacc[mf][3][r] = fmaf(sacc[mf][3][r], SCALE, bv.w);
    }

  // softmax over keys (rows of S^T): per query col, 16 local + 2 shuffles
  float inv[4];
#pragma unroll
  for (int nf = 0; nf < 4; ++nf) {
    float m = sacc[0][nf][0];
#pragma unroll
    for (int mf = 0; mf < 4; ++mf)
#pragma unroll
      for (int r = 0; r < 4; ++r) m = fmaxf(m, sacc[mf][nf][r]);
    m = fmaxf(m, __shfl_xor(m, 16));
    m = fmaxf(m, __shfl_xor(m, 32));
    float sum = 0.f;
#pragma unroll
    for (int mf = 0; mf < 4; ++mf)
#pragma unroll
      for (int r = 0; r < 4; ++r) {
        float e = __expf(sacc[mf][nf][r] - m);
        sacc[mf][nf][r] = e;
        sum += e;
      }
    sum += __shfl_xor(sum, 16);
    sum += __shfl_xor(sum, 32);
    inv[nf] = 1.0f / sum;
  }

  // write P[query][key] (bf16) to LDS, transposed back for PV A-operand
  __hip_bfloat16* pw = P[wave];
#pragma unroll
  for (int mf = 0; mf < 4; ++mf)
#pragma unroll
    for (int r = 0; r < 4; ++r) {
      int key = mf * 16 + (lane >> 4) * 4 + r;
#pragma unroll
      for (int nf = 0; nf < 4; ++nf) {
        int query = nf * 16 + fr;
        pw[query * 72 + key] = __float2bfloat16(sacc[mf][nf][r] * inv[nf]);
      }
    }

  // O = P @ V via MFMA; V^T from per-wave LDS (XOR-swizzled pos)
  f32x4 oacc[4][2] = {};
#pragma unroll
  for (int kk = 0; kk < 2; ++kk) {
    bf16x8 vf[2];
#pragma unroll
    for (int n2 = 0; n2 < 2; ++n2) {
      int d = n2 * 16 + fr;
      vf[n2] = *(const bf16x8*)&vtw[d * 64 + ((kk * 32 + fo) ^ ((d & 7) << 3))];
    }
#pragma unroll
    for (int mf = 0; mf < 4; ++mf) {
      bf16x8 pa = *(const bf16x8*)&pw[(mf * 16 + fr) * 72 + kk * 32 + fo];
#pragma unroll
      for (int n2 = 0; n2 < 2; ++n2)
        oacc[mf][n2] = __builtin_amdgcn_mfma_f32_16x16x32_bf16(
            pa, vf[n2], oacc[mf][n2], 0, 0, 0);
    }
  }

  // store O rows < 49 to windowed [tok49][d32]
#pragma unroll
  for (int mf = 0; mf < 4; ++mf)
#pragma unroll
    for (int r = 0; r < 4; ++r) {
      int row = mf * 16 + (lane >> 4) * 4 + r;
      if (row < 49) {
#pragma unroll
        for (int n2 = 0; n2 < 2; ++n2)
          ab[qkbase + (size_t)row * 32 + n2 * 16 + fr] =
              __float2bfloat16(oacc[mf][n2][r]);
      }
    }
}

// ---------------- K3: output GEMM, bf16 MFMA, counted-vmcnt pipeline (R8) ----------------
__global__ __launch_bounds__(256) void k_out_mfma(
    const __hip_bfloat16* __restrict__ ab, const __hip_bfloat16* __restrict__ wot,
    const int* __restrict__ lutw, const int* __restrict__ luto,
    const float* __restrict__ bias, float* __restrict__ out) {
  __shared__ __align__(16) short As[2][128 * 64];
  __shared__ __align__(16) short Bs[2][128 * 64];
  const int tid = threadIdx.x;
  const int lid = blockIdx.x;                 // 3136 blocks
  const int wid = (lid & 7) * 392 + (lid >> 3);
  const int t0 = (wid >> 2) * 128;
  const int n0 = (wid & 3) * 128;
  const int lane = tid & 63, wave = tid >> 6;
  const int wm = wave >> 1, wn = wave & 1;

  size_t aoff[4];
  const __hip_bfloat16* bsrc[4];
#pragma unroll
  for (int s = 0; s < 4; ++s) {
    int c = s * 256 + tid;
    int row = c >> 3, kc = c & 7;
    aoff[s] = (size_t)lutw[t0 + row] + (size_t)(kc >> 2) * HEAD_STRIDE + (kc & 3) * 8;
    bsrc[s] = wot + (size_t)(n0 + row) * 512 + kc * 8;
  }

  f32x4 acc[4][4] = {};
  const int arow = wm * 64 + (lane & 15);
  const int brow = wn * 64 + (lane & 15);
  const int koff = (lane >> 4) * 8;
  const int sw = (lane & 7) << 3;

  // prologue: stage K-tile 0 into buf 0
#pragma unroll
  for (int s = 0; s < 4; ++s) {
    gload_lds16(ab + aoff[s], (char*)As[0] + wave * 1024 + s * 4096);
    gload_lds16(bsrc[s], (char*)Bs[0] + wave * 1024 + s * 4096);
  }

  for (int t = 0; t < 8; ++t) {
    const int buf = t & 1;
    if (t < 7) {
      const int kt = (t + 1) * 64;
      size_t hoff = (size_t)(kt >> 5) * HEAD_STRIDE;
#pragma unroll
      for (int s = 0; s < 4; ++s) {
        gload_lds16(ab + aoff[s] + hoff, (char*)As[buf ^ 1] + wave * 1024 + s * 4096);
        gload_lds16(bsrc[s] + kt, (char*)Bs[buf ^ 1] + wave * 1024 + s * 4096);
      }
      asm volatile("s_waitcnt vmcnt(8)" ::: "memory");
    } else {
      asm volatile("s_waitcnt vmcnt(0)" ::: "memory");
    }
    __builtin_amdgcn_s_barrier();
    __builtin_amdgcn_sched_barrier(0);

    bf16x8 af[2][4], bfr[2][4];
#pragma unroll
    for (int kk = 0; kk < 2; ++kk) {
      const int eo = kk * 32 + koff;
#pragma unroll
      for (int mf = 0; mf < 4; ++mf)
        af[kk][mf] = *(const bf16x8*)&As[buf][(arow + mf * 16) * 64 + eo];
#pragma unroll
      for (int nf = 0; nf < 4; ++nf)
        bfr[kk][nf] = *(const bf16x8*)&Bs[buf][(brow + nf * 16) * 64 + (eo ^ sw)];
    }
    __builtin_amdgcn_s_setprio(1);
#pragma unroll
    for (int kk = 0; kk < 2; ++kk)
#pragma unroll
      for (int mf = 0; mf < 4; ++mf)
#pragma unroll
        for (int nf = 0; nf < 4; ++nf)
          acc[mf][nf] = __builtin_amdgcn_mfma_f32_16x16x32_bf16(
              af[kk][mf], bfr[kk][nf], acc[mf][nf], 0, 0, 0);
    __builtin_amdgcn_s_setprio(0);
    __builtin_amdgcn_s_barrier();
    __builtin_amdgcn_sched_barrier(0);
  }

  float bia[4];
#pragma unroll
  for (int nf = 0; nf < 4; ++nf)
    bia[nf] = bias[n0 + wn * 64 + nf * 16 + (lane & 15)];

  const int tbase = t0 + wm * 64 + (lane >> 4) * 4;
  int ooff[4][4];
#pragma unroll
  for (int mf = 0; mf < 4; ++mf)
#pragma unroll
    for (int r = 0; r < 4; ++r)
      ooff[mf][r] = luto[tbase + mf * 16 + r];
#pragma unroll
  for (int mf = 0; mf < 4; ++mf) {
#pragma unroll
    for (int r = 0; r < 4; ++r) {
      float* op = out + (size_t)ooff[mf][r] + n0 + wn * 64 + (lane & 15);
#pragma unroll
      for (int nf = 0; nf < 4; ++nf) op[nf * 16] = acc[mf][nf][r] + bia[nf];
    }
  }
}

extern "C" void kernel_launch(void* const* d_in, const int* in_sizes, int n_in,
                              void* d_out, int out_size, void* d_ws, size_t ws_size,
                              hipStream_t stream) {
  const float* x     = (const float*)d_in[0];
  const float* w_qkv = (const float*)d_in[1];
  const float* pe    = (const float*)d_in[2];
  const float* w_out = (const float*)d_in[3];
  const float* b_out = (const float*)d_in[4];
  float* out = (float*)d_out;

  __hip_bfloat16* qb  = (__hip_bfloat16*)d_ws;          // 51,380,224
  __hip_bfloat16* kb  = qb + (size_t)QKV_ELEMS;         // 51,380,224
  __hip_bfloat16* vb  = kb + (size_t)QKV_ELEMS;         // 51,380,224
  __hip_bfloat16* xb  = vb + (size_t)QKV_ELEMS;         // 51,380,224 (aliased ab)
  __hip_bfloat16* ab  = xb;
  __hip_bfloat16* wbt = xb + (size_t)QKV_ELEMS;         // 786,432
  __hip_bfloat16* wot = wbt + (size_t)(1536 * 512);     // 262,144
  float* biasT = (float*)(wot + (size_t)(512 * 512));   // 262,144 f32 (1 MB)
  int* lutw = (int*)(biasT + 262144);                   // 100,352 int
  int* luto = lutw + NTOKENS;                           // 100,352 int

  k_prep_lut<<<dim3(392), dim3(256), 0, stream>>>(lutw, luto);
  k_prep_x<<<dim3(6272), dim3(256), 0, stream>>>(x, xb);
  k_transpose<<<dim3(24, 8), dim3(256), 0, stream>>>(w_qkv, wbt, 512, 1536);
  k_transpose<<<dim3(8, 8), dim3(256), 0, stream>>>(w_out, wot, 512, 512);
  k_prep_bias<<<dim3(1024), dim3(256), 0, stream>>>(pe, biasT);
  k_qkv_mfma<<<dim3(4704), dim3(256), 0, stream>>>(xb, wbt, lutw, qb, kb, vb);
  k_attn_mfma<<<dim3(8192), dim3(256), 0, stream>>>(qb, kb, vb, biasT, ab);
  k_out_mfma<<<dim3(3136), dim3(256), 0, stream>>>(ab, wot, lutw, luto, b_out, out);
}

// Round 11
// 550.939 us; speedup vs baseline: 1.5797x; 1.1420x over previous
//
#include <hip/hip_runtime.h>
#include <hip/hip_bf16.h>
#include <stdint.h>

// Swin window attention, B=32, H=W=56, DIM=512, HEADS=16, HD=32, WS=7, shift=3.
// Round 11: revert R10. k_qkv -> 3-LDS-buffer counted pipeline, 512 threads /
// 8 waves (wave 64x64, same frag math as R8): while computing tile t (buf t%3)
// stage tile t+2 into buf (t+2)%3 (dead since tile t-1 => race-free), vmcnt(6)
// at tile entry (never 0 mid-loop), ONE barrier per K-tile. k_attn + setprio
// (T5, independent-wave regime). k_out / preps = R8 verbatim.

#define NWIN 64
#define NTOK 49
#define WIN_ELEMS 1568        // 49*32
#define HEAD_STRIDE 100352    // 64*49*32
#define BATCH_STRIDE 1605632  // 16*64*49*32
#define QKV_ELEMS 51380224    // 32*16*64*49*32
#define NTOKENS 100352
#define SCALE 0.17677669529663687f

typedef __attribute__((ext_vector_type(8))) short bf16x8;
typedef __attribute__((ext_vector_type(4))) float f32x4;

#define AS1 __attribute__((address_space(1)))
#define AS3 __attribute__((address_space(3)))

struct __align__(16) bf8 { __hip_bfloat16 h[8]; };

__device__ __forceinline__ void gload_lds16(const void* g, void* l) {
  __builtin_amdgcn_global_load_lds((const AS1 unsigned int*)g,
                                   (AS3 unsigned int*)l, 16, 0, 0);
}

__device__ __forceinline__ void token_decode(int t, int& b, int& i, int& j) {
  b = t / 3136;
  int r = t - b * 3136;
  i = r / 56;
  j = r - i * 56;
}

// ---------------- P0: token offset LUTs ----------------
__global__ __launch_bounds__(256) void k_prep_lut(int* __restrict__ lutw,
                                                  int* __restrict__ luto) {
  int t = blockIdx.x * 256 + threadIdx.x;       // 392 blocks
  int b, i, j;
  token_decode(t, b, i, j);
  int win = (i / 7) * 8 + (j / 7);
  int pos = (i % 7) * 7 + (j % 7);
  lutw[t] = b * BATCH_STRIDE + win * WIN_ELEMS + pos * 32;
  int di = i + 3; if (di >= 56) di -= 56;
  int dj = j + 3; if (dj >= 56) dj -= 56;
  luto[t] = ((b * 56 + di) * 56 + dj) * 512;
}

// ---------------- P1: x -> bf16, roll(-3,-3), SWIZZLED slot store ----------------
__global__ __launch_bounds__(256) void k_prep_x(const float* __restrict__ x,
                                                __hip_bfloat16* __restrict__ xb) {
  int idx = blockIdx.x * 256 + threadIdx.x;
  int t = idx >> 6;
  int g = idx & 63;
  int b, i, j;
  token_decode(t, b, i, j);
  int si = i + 3; if (si >= 56) si -= 56;
  int sj = j + 3; if (sj >= 56) sj -= 56;
  const float* src = x + ((size_t)(b * 56 + si) * 56 + sj) * 512 + g * 8;
  float4 a0 = *(const float4*)src;
  float4 a1 = *(const float4*)(src + 4);
  bf8 o;
  o.h[0] = __float2bfloat16(a0.x); o.h[1] = __float2bfloat16(a0.y);
  o.h[2] = __float2bfloat16(a0.z); o.h[3] = __float2bfloat16(a0.w);
  o.h[4] = __float2bfloat16(a1.x); o.h[5] = __float2bfloat16(a1.y);
  o.h[6] = __float2bfloat16(a1.z); o.h[7] = __float2bfloat16(a1.w);
  int slot = ((g * 8) ^ ((t & 7) << 3));
  *(bf8*)(xb + (size_t)t * 512 + slot) = o;
}

// ---------------- P2/P3: fp32 [K][N] -> bf16 [N][K] transpose, SWIZZLED ----------------
__global__ __launch_bounds__(256) void k_transpose(const float* __restrict__ in,
                                                   __hip_bfloat16* __restrict__ out,
                                                   int K, int N) {
  __shared__ float tl[64][65];
  const int nb = blockIdx.x * 64, kb = blockIdx.y * 64;
  const int tid = threadIdx.x;
#pragma unroll
  for (int s = 0; s < 16; ++s) {
    int idx = s * 256 + tid; int r = idx >> 6, c = idx & 63;
    tl[r][c] = in[(size_t)(kb + r) * N + nb + c];
  }
  __syncthreads();
#pragma unroll
  for (int s = 0; s < 16; ++s) {
    int idx = s * 256 + tid; int r = idx >> 6, c = idx & 63;
    int row = nb + r;
    int col = (kb + c) ^ ((row & 7) << 3);
    out[(size_t)row * K + col] = __float2bfloat16(tl[c][r]);
  }
}

// ---------------- P4: bias table in MFMA fragment layout ----------------
__global__ __launch_bounds__(256) void k_prep_bias(const float* __restrict__ pe,
                                                   float* __restrict__ biasT) {
  int id = blockIdx.x * 256 + threadIdx.x;      // 262144 total
  int whid = id >> 12;
  int wtype = whid >> 4, h = whid & 15;
  int mid = id & 4095;
  int mf = mid >> 10, r = (mid >> 8) & 3, lane = (mid >> 2) & 63, nf = mid & 3;
  int key = mf * 16 + (lane >> 4) * 4 + r;
  int query = nf * 16 + (lane & 15);
  float v;
  if (key >= 49 || query >= 49) {
    v = -1e30f;
  } else {
    int i = query, j = key;
    int xi = i / 7, yi = i - xi * 7;
    int xj = j / 7, yj = j - xj * 7;
    int dx = xj - xi; if (dx < 0) dx += 13;
    int dy = yj - yi; if (dy < 0) dy += 13;
    v = pe[(dx * 13 + dy) * 16 + h];
    if ((wtype & 1) && ((xi >= 4) != (xj >= 4))) v = -1e30f;
    if ((wtype & 2) && ((yi >= 4) != (yj >= 4))) v = -1e30f;
  }
  biasT[id] = v;
}

// ---------------- K1: QKV GEMM, 3-buffer counted pipeline ----------------
// M=100352, N=1536, K=512. 256x128 block tile, 512 thr / 8 waves (4M x 2N),
// wave 64x64 (acc[4][4]). Stage tile t+2 -> buf (t+2)%3 while computing t.
__global__ __launch_bounds__(512) void k_qkv_mfma(
    const __hip_bfloat16* __restrict__ xb, const __hip_bfloat16* __restrict__ wbt,
    const int* __restrict__ lutw,
    __hip_bfloat16* __restrict__ qb, __hip_bfloat16* __restrict__ kb,
    __hip_bfloat16* __restrict__ vb) {
  __shared__ __align__(16) short As[3][256 * 64];   // 3 x 32 KB
  __shared__ __align__(16) short Bs[3][128 * 64];   // 3 x 16 KB
  const int tid = threadIdx.x;                 // 0..511
  const int lid = blockIdx.x;                  // 4704 blocks
  const int wid = (lid & 7) * 588 + (lid >> 3);
  const int t0 = (wid / 12) * 256;
  const int n0 = (wid % 12) * 128;
  const int lane = tid & 63, wave = tid >> 6;  // 8 waves
  const int wm = wave >> 1, wn = wave & 1;     // 4M x 2N

  // staging sources: chunk c = s*512+tid -> row c>>3, k-chunk c&7 (swizzled at producer)
  const __hip_bfloat16* asrc[4];
#pragma unroll
  for (int s = 0; s < 4; ++s) {
    int c = s * 512 + tid;
    asrc[s] = xb + (size_t)(t0 + (c >> 3)) * 512 + (c & 7) * 8;
  }
  const __hip_bfloat16* bsrc[2];
#pragma unroll
  for (int s = 0; s < 2; ++s) {
    int c = s * 512 + tid;
    bsrc[s] = wbt + (size_t)(n0 + (c >> 3)) * 512 + (c & 7) * 8;
  }
  const int lofs = wave * 1024;                // per-wave linear dst offset

  f32x4 acc[4][4] = {};
  const int arow = wm * 64 + (lane & 15);
  const int brow = wn * 64 + (lane & 15);
  const int koff = (lane >> 4) * 8;
  const int sw = (lane & 7) << 3;              // row&7 == lane&7 for fragments

  // prologue: stage tiles 0 (buf0) and 1 (buf1); 6 loads each, issue order = tile order
#pragma unroll
  for (int s = 0; s < 4; ++s) gload_lds16(asrc[s], (char*)As[0] + s * 8192 + lofs);
#pragma unroll
  for (int s = 0; s < 2; ++s) gload_lds16(bsrc[s], (char*)Bs[0] + s * 8192 + lofs);
#pragma unroll
  for (int s = 0; s < 4; ++s) gload_lds16(asrc[s] + 64, (char*)As[1] + s * 8192 + lofs);
#pragma unroll
  for (int s = 0; s < 2; ++s) gload_lds16(bsrc[s] + 64, (char*)Bs[1] + s * 8192 + lofs);

  int bufc = 0;
  for (int t = 0; t < 8; ++t) {
    if (t == 7) asm volatile("s_waitcnt vmcnt(0)" ::: "memory");
    else        asm volatile("s_waitcnt vmcnt(6)" ::: "memory");  // tile t landed; t+1 in flight
    __builtin_amdgcn_s_barrier();          // all waves: tile t visible, buf (t+2)%3 dead
    __builtin_amdgcn_sched_barrier(0);
    const short* Ab = As[bufc];
    const short* Bb = Bs[bufc];
    const int bufs = (bufc + 2 >= 3) ? bufc - 1 : bufc + 2;   // (t+2)%3
    const int kts = (t + 2) * 64;
    const bool pf = (t < 6);

    // ---- phase kk=0 ----
    {
      const int eo = koff ^ sw;
      bf16x8 af[4], bfr[4];
#pragma unroll
      for (int mf = 0; mf < 4; ++mf)
        af[mf] = *(const bf16x8*)&Ab[(arow + mf * 16) * 64 + eo];
#pragma unroll
      for (int nf = 0; nf < 4; ++nf)
        bfr[nf] = *(const bf16x8*)&Bb[(brow + nf * 16) * 64 + eo];
      if (pf) {
        gload_lds16(asrc[0] + kts, (char*)As[bufs] + 0 * 8192 + lofs);
        gload_lds16(asrc[1] + kts, (char*)As[bufs] + 1 * 8192 + lofs);
        gload_lds16(asrc[2] + kts, (char*)As[bufs] + 2 * 8192 + lofs);
      }
      asm volatile("s_waitcnt lgkmcnt(0)" ::: "memory");
      __builtin_amdgcn_sched_barrier(0);
      __builtin_amdgcn_s_setprio(1);
#pragma unroll
      for (int mf = 0; mf < 4; ++mf)
#pragma unroll
        for (int nf = 0; nf < 4; ++nf)
          acc[mf][nf] = __builtin_amdgcn_mfma_f32_16x16x32_bf16(
              af[mf], bfr[nf], acc[mf][nf], 0, 0, 0);
      __builtin_amdgcn_s_setprio(0);
    }
    // ---- phase kk=1 ----
    {
      const int eo = (32 + koff) ^ sw;
      bf16x8 af[4], bfr[4];
#pragma unroll
      for (int mf = 0; mf < 4; ++mf)
        af[mf] = *(const bf16x8*)&Ab[(arow + mf * 16) * 64 + eo];
#pragma unroll
      for (int nf = 0; nf < 4; ++nf)
        bfr[nf] = *(const bf16x8*)&Bb[(brow + nf * 16) * 64 + eo];
      if (pf) {
        gload_lds16(asrc[3] + kts, (char*)As[bufs] + 3 * 8192 + lofs);
        gload_lds16(bsrc[0] + kts, (char*)Bs[bufs] + 0 * 8192 + lofs);
        gload_lds16(bsrc[1] + kts, (char*)Bs[bufs] + 1 * 8192 + lofs);
      }
      asm volatile("s_waitcnt lgkmcnt(0)" ::: "memory");
      __builtin_amdgcn_sched_barrier(0);
      __builtin_amdgcn_s_setprio(1);
#pragma unroll
      for (int mf = 0; mf < 4; ++mf)
#pragma unroll
        for (int nf = 0; nf < 4; ++nf)
          acc[mf][nf] = __builtin_amdgcn_mfma_f32_16x16x32_bf16(
              af[mf], bfr[nf], acc[mf][nf], 0, 0, 0);
      __builtin_amdgcn_s_setprio(0);
    }
    bufc = (bufc == 2) ? 0 : bufc + 1;
  }

  // epilogue: q/k/v -> windowed [b][h][win][pos49][d32]; offsets via LUT
  __hip_bfloat16* obs[4];
#pragma unroll
  for (int nf = 0; nf < 4; ++nf) {
    int n = n0 + wn * 64 + nf * 16 + (lane & 15);
    int sp = n >> 9, hc = n & 511, h = hc >> 5, d = hc & 31;
    obs[nf] = (sp == 0 ? qb : (sp == 1 ? kb : vb)) + (size_t)h * HEAD_STRIDE + d;
  }
  const int tbase = t0 + wm * 64 + (lane >> 4) * 4;
  int woff[4][4];
#pragma unroll
  for (int mf = 0; mf < 4; ++mf)
#pragma unroll
    for (int r = 0; r < 4; ++r)
      woff[mf][r] = lutw[tbase + mf * 16 + r];
#pragma unroll
  for (int mf = 0; mf < 4; ++mf)
#pragma unroll
    for (int r = 0; r < 4; ++r) {
      size_t off = (size_t)woff[mf][r];
#pragma unroll
      for (int nf = 0; nf < 4; ++nf)
        obs[nf][off] = __float2bfloat16(acc[mf][nf][r]);
    }
}

// ---------------- K2: attention via MFMA, one wave per (b,h,win) ----------------
__global__ __launch_bounds__(256) void k_attn_mfma(
    const __hip_bfloat16* __restrict__ qb, const __hip_bfloat16* __restrict__ kb,
    const __hip_bfloat16* __restrict__ vb, const float* __restrict__ biasT,
    __hip_bfloat16* __restrict__ ab) {
  __shared__ __align__(16) __hip_bfloat16 P[4][64 * 72];   // per-wave P[query][key]
  __shared__ __align__(16) __hip_bfloat16 VT[4][32 * 64];  // per-wave V^T[d][pos^swz]
  const int tid = threadIdx.x, lane = tid & 63, wave = tid >> 6;
  const int gid = blockIdx.x * 4 + wave;                   // (b*16+h)*64 + win
  const int win = gid & 63, h = (gid >> 6) & 15;
  const int wtype = (((win >> 3) == 7) ? 1 : 0) | (((win & 7) == 7) ? 2 : 0);
  const size_t qkbase = (size_t)gid * WIN_ELEMS;
  const int fr = lane & 15, fo = (lane >> 4) * 8;

  // issue V loads early (196 bf8 chunks over 64 lanes, 4 iters)
  bf8 v8[4];
#pragma unroll
  for (int it = 0; it < 4; ++it) {
    int c = it * 64 + lane;
    if (c < 196) v8[it] = *(const bf8*)(vb + qkbase + (size_t)c * 8);
  }

  // Q,K fragments straight from global ([tok][d32], d==K of MFMA)
  bf16x8 kf[4], qf[4];
#pragma unroll
  for (int f = 0; f < 4; ++f) {
    kf[f] = *(const bf16x8*)(kb + qkbase + (size_t)(f * 16 + fr) * 32 + fo);
    qf[f] = *(const bf16x8*)(qb + qkbase + (size_t)(f * 16 + fr) * 32 + fo);
  }

  // zero VT (pads pos 49..63 and unwritten rows), then transpose V into it
  __hip_bfloat16* vtw = VT[wave];
  {
    bf16x8 zz = {};
#pragma unroll
    for (int z = 0; z < 4; ++z) *(bf16x8*)&vtw[z * 512 + lane * 8] = zz;
  }
#pragma unroll
  for (int it = 0; it < 4; ++it) {
    int c = it * 64 + lane;
    if (c < 196) {
      int pos = c >> 2, d0 = (c & 3) * 8;
#pragma unroll
      for (int u = 0; u < 8; ++u) {
        int d = d0 + u;
        vtw[d * 64 + (pos ^ ((d & 7) << 3))] = v8[it].h[u];
      }
    }
  }

  // S^T[key][query] = K @ Q^T
  f32x4 sacc[4][4] = {};   // [key-frag mf][query-frag nf]
  __builtin_amdgcn_s_setprio(1);
#pragma unroll
  for (int mf = 0; mf < 4; ++mf)
#pragma unroll
    for (int nf = 0; nf < 4; ++nf)
      sacc[mf][nf] = __builtin_amdgcn_mfma_f32_16x16x32_bf16(
          kf[mf], qf[nf], sacc[mf][nf], 0, 0, 0);
  __builtin_amdgcn_s_setprio(0);

  // scale + bias/mask table (fragment-layout, coalesced float4)
  const float* bp = biasT + (size_t)(wtype * 16 + h) * 4096;
#pragma unroll
  for (int mf = 0; mf < 4; ++mf)
#pragma unroll
    for (int r = 0; r < 4; ++r) {
      float4 bv = *(const float4*)(bp + ((mf * 4 + r) * 64 + lane) * 4);
      sacc[mf][0][r] = fmaf(sacc[mf][0][r], SCALE, bv.x);
      sacc[mf][1][r] = fmaf(sacc[mf][1][r], SCALE, bv.y);
      sacc[mf][2][r] = fmaf(sacc[mf][2][r], SCALE, bv.z);
      sacc[mf][3][r] = fmaf(sacc[mf][3][r], SCALE, bv.w);
    }

  // softmax over keys (rows of S^T): per query col, 16 local + 2 shuffles
  float inv[4];
#pragma unroll
  for (int nf = 0; nf < 4; ++nf) {
    float m = sacc[0][nf][0];
#pragma unroll
    for (int mf = 0; mf < 4; ++mf)
#pragma unroll
      for (int r = 0; r < 4; ++r) m = fmaxf(m, sacc[mf][nf][r]);
    m = fmaxf(m, __shfl_xor(m, 16));
    m = fmaxf(m, __shfl_xor(m, 32));
    float sum = 0.f;
#pragma unroll
    for (int mf = 0; mf < 4; ++mf)
#pragma unroll
      for (int r = 0; r < 4; ++r) {
        float e = __expf(sacc[mf][nf][r] - m);
        sacc[mf][nf][r] = e;
        sum += e;
      }
    sum += __shfl_xor(sum, 16);
    sum += __shfl_xor(sum, 32);
    inv[nf] = 1.0f / sum;
  }

  // write P[query][key] (bf16) to LDS, transposed back for PV A-operand
  __hip_bfloat16* pw = P[wave];
#pragma unroll
  for (int mf = 0; mf < 4; ++mf)
#pragma unroll
    for (int r = 0; r < 4; ++r) {
      int key = mf * 16 + (lane >> 4) * 4 + r;
#pragma unroll
      for (int nf = 0; nf < 4; ++nf) {
        int query = nf * 16 + fr;
        pw[query * 72 + key] = __float2bfloat16(sacc[mf][nf][r] * inv[nf]);
      }
    }

  // O = P @ V via MFMA; V^T from per-wave LDS (XOR-swizzled pos)
  f32x4 oacc[4][2] = {};
#pragma unroll
  for (int kk = 0; kk < 2; ++kk) {
    bf16x8 vf[2];
#pragma unroll
    for (int n2 = 0; n2 < 2; ++n2) {
      int d = n2 * 16 + fr;
      vf[n2] = *(const bf16x8*)&vtw[d * 64 + ((kk * 32 + fo) ^ ((d & 7) << 3))];
    }
    __builtin_amdgcn_s_setprio(1);
#pragma unroll
    for (int mf = 0; mf < 4; ++mf) {
      bf16x8 pa = *(const bf16x8*)&pw[(mf * 16 + fr) * 72 + kk * 32 + fo];
#pragma unroll
      for (int n2 = 0; n2 < 2; ++n2)
        oacc[mf][n2] = __builtin_amdgcn_mfma_f32_16x16x32_bf16(
            pa, vf[n2], oacc[mf][n2], 0, 0, 0);
    }
    __builtin_amdgcn_s_setprio(0);
  }

  // store O rows < 49 to windowed [tok49][d32]
#pragma unroll
  for (int mf = 0; mf < 4; ++mf)
#pragma unroll
    for (int r = 0; r < 4; ++r) {
      int row = mf * 16 + (lane >> 4) * 4 + r;
      if (row < 49) {
#pragma unroll
        for (int n2 = 0; n2 < 2; ++n2)
          ab[qkbase + (size_t)row * 32 + n2 * 16 + fr] =
              __float2bfloat16(oacc[mf][n2][r]);
      }
    }
}

// ---------------- K3: output GEMM, bf16 MFMA, counted-vmcnt pipeline (R8) ----------------
__global__ __launch_bounds__(256) void k_out_mfma(
    const __hip_bfloat16* __restrict__ ab, const __hip_bfloat16* __restrict__ wot,
    const int* __restrict__ lutw, const int* __restrict__ luto,
    const float* __restrict__ bias, float* __restrict__ out) {
  __shared__ __align__(16) short As[2][128 * 64];
  __shared__ __align__(16) short Bs[2][128 * 64];
  const int tid = threadIdx.x;
  const int lid = blockIdx.x;                 // 3136 blocks
  const int wid = (lid & 7) * 392 + (lid >> 3);
  const int t0 = (wid >> 2) * 128;
  const int n0 = (wid & 3) * 128;
  const int lane = tid & 63, wave = tid >> 6;
  const int wm = wave >> 1, wn = wave & 1;

  size_t aoff[4];
  const __hip_bfloat16* bsrc[4];
#pragma unroll
  for (int s = 0; s < 4; ++s) {
    int c = s * 256 + tid;
    int row = c >> 3, kc = c & 7;
    aoff[s] = (size_t)lutw[t0 + row] + (size_t)(kc >> 2) * HEAD_STRIDE + (kc & 3) * 8;
    bsrc[s] = wot + (size_t)(n0 + row) * 512 + kc * 8;
  }

  f32x4 acc[4][4] = {};
  const int arow = wm * 64 + (lane & 15);
  const int brow = wn * 64 + (lane & 15);
  const int koff = (lane >> 4) * 8;
  const int sw = (lane & 7) << 3;

  // prologue: stage K-tile 0 into buf 0
#pragma unroll
  for (int s = 0; s < 4; ++s) {
    gload_lds16(ab + aoff[s], (char*)As[0] + wave * 1024 + s * 4096);
    gload_lds16(bsrc[s], (char*)Bs[0] + wave * 1024 + s * 4096);
  }

  for (int t = 0; t < 8; ++t) {
    const int buf = t & 1;
    if (t < 7) {
      const int kt = (t + 1) * 64;
      size_t hoff = (size_t)(kt >> 5) * HEAD_STRIDE;
#pragma unroll
      for (int s = 0; s < 4; ++s) {
        gload_lds16(ab + aoff[s] + hoff, (char*)As[buf ^ 1] + wave * 1024 + s * 4096);
        gload_lds16(bsrc[s] + kt, (char*)Bs[buf ^ 1] + wave * 1024 + s * 4096);
      }
      asm volatile("s_waitcnt vmcnt(8)" ::: "memory");
    } else {
      asm volatile("s_waitcnt vmcnt(0)" ::: "memory");
    }
    __builtin_amdgcn_s_barrier();
    __builtin_amdgcn_sched_barrier(0);

    bf16x8 af[2][4], bfr[2][4];
#pragma unroll
    for (int kk = 0; kk < 2; ++kk) {
      const int eo = kk * 32 + koff;
#pragma unroll
      for (int mf = 0; mf < 4; ++mf)
        af[kk][mf] = *(const bf16x8*)&As[buf][(arow + mf * 16) * 64 + eo];
#pragma unroll
      for (int nf = 0; nf < 4; ++nf)
        bfr[kk][nf] = *(const bf16x8*)&Bs[buf][(brow + nf * 16) * 64 + (eo ^ sw)];
    }
    __builtin_amdgcn_s_setprio(1);
#pragma unroll
    for (int kk = 0; kk < 2; ++kk)
#pragma unroll
      for (int mf = 0; mf < 4; ++mf)
#pragma unroll
        for (int nf = 0; nf < 4; ++nf)
          acc[mf][nf] = __builtin_amdgcn_mfma_f32_16x16x32_bf16(
              af[kk][mf], bfr[kk][nf], acc[mf][nf], 0, 0, 0);
    __builtin_amdgcn_s_setprio(0);
    __builtin_amdgcn_s_barrier();
    __builtin_amdgcn_sched_barrier(0);
  }

  float bia[4];
#pragma unroll
  for (int nf = 0; nf < 4; ++nf)
    bia[nf] = bias[n0 + wn * 64 + nf * 16 + (lane & 15)];

  const int tbase = t0 + wm * 64 + (lane >> 4) * 4;
  int ooff[4][4];
#pragma unroll
  for (int mf = 0; mf < 4; ++mf)
#pragma unroll
    for (int r = 0; r < 4; ++r)
      ooff[mf][r] = luto[tbase + mf * 16 + r];
#pragma unroll
  for (int mf = 0; mf < 4; ++mf) {
#pragma unroll
    for (int r = 0; r < 4; ++r) {
      float* op = out + (size_t)ooff[mf][r] + n0 + wn * 64 + (lane & 15);
#pragma unroll
      for (int nf = 0; nf < 4; ++nf) op[nf * 16] = acc[mf][nf][r] + bia[nf];
    }
  }
}

extern "C" void kernel_launch(void* const* d_in, const int* in_sizes, int n_in,
                              void* d_out, int out_size, void* d_ws, size_t ws_size,
                              hipStream_t stream) {
  const float* x     = (const float*)d_in[0];
  const float* w_qkv = (const float*)d_in[1];
  const float* pe    = (const float*)d_in[2];
  const float* w_out = (const float*)d_in[3];
  const float* b_out = (const float*)d_in[4];
  float* out = (float*)d_out;

  __hip_bfloat16* qb  = (__hip_bfloat16*)d_ws;          // 51,380,224
  __hip_bfloat16* kb  = qb + (size_t)QKV_ELEMS;         // 51,380,224
  __hip_bfloat16* vb  = kb + (size_t)QKV_ELEMS;         // 51,380,224
  __hip_bfloat16* xb  = vb + (size_t)QKV_ELEMS;         // 51,380,224 (aliased ab)
  __hip_bfloat16* ab  = xb;
  __hip_bfloat16* wbt = xb + (size_t)QKV_ELEMS;         // 786,432
  __hip_bfloat16* wot = wbt + (size_t)(1536 * 512);     // 262,144
  float* biasT = (float*)(wot + (size_t)(512 * 512));   // 262,144 f32 (1 MB)
  int* lutw = (int*)(biasT + 262144);                   // 100,352 int
  int* luto = lutw + NTOKENS;                           // 100,352 int

  k_prep_lut<<<dim3(392), dim3(256), 0, stream>>>(lutw, luto);
  k_prep_x<<<dim3(25088), dim3(256), 0, stream>>>(x, xb);
  k_transpose<<<dim3(24, 8), dim3(256), 0, stream>>>(w_qkv, wbt, 512, 1536);
  k_transpose<<<dim3(8, 8), dim3(256), 0, stream>>>(w_out, wot, 512, 512);
  k_prep_bias<<<dim3(1024), dim3(256), 0, stream>>>(pe, biasT);
  k_qkv_mfma<<<dim3(4704), dim3(512), 0, stream>>>(xb, wbt, lutw, qb, kb, vb);
  k_attn_mfma<<<dim3(8192), dim3(256), 0, stream>>>(qb, kb, vb, biasT, ab);
  k_out_mfma<<<dim3(3136), dim3(256), 0, stream>>>(ab, wot, lutw, luto, b_out, out);
}

// Round 12
// 538.440 us; speedup vs baseline: 1.6164x; 1.0232x over previous
//
#include <hip/hip_runtime.h>
#include <hip/hip_bf16.h>
#include <stdint.h>

// Swin window attention, B=32, H=W=56, DIM=512, HEADS=16, HD=32, WS=7, shift=3.
// Round 12: k_qkv reverted to R8 exactly (262us floor; 4 structural attempts all
// null/regressed). k_attn: V LDS round-trip removed — PV B-fragments gathered
// directly from global (hoisted scalar loads, L2-resident), LDS 53->37KB
// (4 blocks/CU), P-store packed to b32. k_out / preps unchanged.

#define NWIN 64
#define NTOK 49
#define WIN_ELEMS 1568        // 49*32
#define HEAD_STRIDE 100352    // 64*49*32
#define BATCH_STRIDE 1605632  // 16*64*49*32
#define QKV_ELEMS 51380224    // 32*16*64*49*32
#define NTOKENS 100352
#define SCALE 0.17677669529663687f

typedef __attribute__((ext_vector_type(8))) short bf16x8;
typedef __attribute__((ext_vector_type(4))) float f32x4;

#define AS1 __attribute__((address_space(1)))
#define AS3 __attribute__((address_space(3)))

struct __align__(16) bf8 { __hip_bfloat16 h[8]; };

__device__ __forceinline__ void gload_lds16(const void* g, void* l) {
  __builtin_amdgcn_global_load_lds((const AS1 unsigned int*)g,
                                   (AS3 unsigned int*)l, 16, 0, 0);
}

__device__ __forceinline__ void token_decode(int t, int& b, int& i, int& j) {
  b = t / 3136;
  int r = t - b * 3136;
  i = r / 56;
  j = r - i * 56;
}

__device__ __forceinline__ unsigned pack_bf2(float a, float b) {
  __hip_bfloat16 x = __float2bfloat16(a), y = __float2bfloat16(b);
  unsigned short ux = *(unsigned short*)&x, uy = *(unsigned short*)&y;
  return (unsigned)ux | ((unsigned)uy << 16);
}

// ---------------- P0: token offset LUTs ----------------
__global__ __launch_bounds__(256) void k_prep_lut(int* __restrict__ lutw,
                                                  int* __restrict__ luto) {
  int t = blockIdx.x * 256 + threadIdx.x;       // 392 blocks
  int b, i, j;
  token_decode(t, b, i, j);
  int win = (i / 7) * 8 + (j / 7);
  int pos = (i % 7) * 7 + (j % 7);
  lutw[t] = b * BATCH_STRIDE + win * WIN_ELEMS + pos * 32;
  int di = i + 3; if (di >= 56) di -= 56;
  int dj = j + 3; if (dj >= 56) dj -= 56;
  luto[t] = ((b * 56 + di) * 56 + dj) * 512;
}

// ---------------- P1: x -> bf16, roll(-3,-3), SWIZZLED slot store ----------------
__global__ __launch_bounds__(256) void k_prep_x(const float* __restrict__ x,
                                                __hip_bfloat16* __restrict__ xb) {
  int idx = blockIdx.x * 256 + threadIdx.x;
  int t = idx >> 6;
  int g = idx & 63;
  int b, i, j;
  token_decode(t, b, i, j);
  int si = i + 3; if (si >= 56) si -= 56;
  int sj = j + 3; if (sj >= 56) sj -= 56;
  const float* src = x + ((size_t)(b * 56 + si) * 56 + sj) * 512 + g * 8;
  float4 a0 = *(const float4*)src;
  float4 a1 = *(const float4*)(src + 4);
  bf8 o;
  o.h[0] = __float2bfloat16(a0.x); o.h[1] = __float2bfloat16(a0.y);
  o.h[2] = __float2bfloat16(a0.z); o.h[3] = __float2bfloat16(a0.w);
  o.h[4] = __float2bfloat16(a1.x); o.h[5] = __float2bfloat16(a1.y);
  o.h[6] = __float2bfloat16(a1.z); o.h[7] = __float2bfloat16(a1.w);
  int slot = ((g * 8) ^ ((t & 7) << 3));
  *(bf8*)(xb + (size_t)t * 512 + slot) = o;
}

// ---------------- P2/P3: fp32 [K][N] -> bf16 [N][K] transpose, SWIZZLED ----------------
__global__ __launch_bounds__(256) void k_transpose(const float* __restrict__ in,
                                                   __hip_bfloat16* __restrict__ out,
                                                   int K, int N) {
  __shared__ float tl[64][65];
  const int nb = blockIdx.x * 64, kb = blockIdx.y * 64;
  const int tid = threadIdx.x;
#pragma unroll
  for (int s = 0; s < 16; ++s) {
    int idx = s * 256 + tid; int r = idx >> 6, c = idx & 63;
    tl[r][c] = in[(size_t)(kb + r) * N + nb + c];
  }
  __syncthreads();
#pragma unroll
  for (int s = 0; s < 16; ++s) {
    int idx = s * 256 + tid; int r = idx >> 6, c = idx & 63;
    int row = nb + r;
    int col = (kb + c) ^ ((row & 7) << 3);
    out[(size_t)row * K + col] = __float2bfloat16(tl[c][r]);
  }
}

// ---------------- P4: bias table in MFMA fragment layout ----------------
__global__ __launch_bounds__(256) void k_prep_bias(const float* __restrict__ pe,
                                                   float* __restrict__ biasT) {
  int id = blockIdx.x * 256 + threadIdx.x;      // 262144 total
  int whid = id >> 12;
  int wtype = whid >> 4, h = whid & 15;
  int mid = id & 4095;
  int mf = mid >> 10, r = (mid >> 8) & 3, lane = (mid >> 2) & 63, nf = mid & 3;
  int key = mf * 16 + (lane >> 4) * 4 + r;
  int query = nf * 16 + (lane & 15);
  float v;
  if (key >= 49 || query >= 49) {
    v = -1e30f;
  } else {
    int i = query, j = key;
    int xi = i / 7, yi = i - xi * 7;
    int xj = j / 7, yj = j - xj * 7;
    int dx = xj - xi; if (dx < 0) dx += 13;
    int dy = yj - yi; if (dy < 0) dy += 13;
    v = pe[(dx * 13 + dy) * 16 + h];
    if ((wtype & 1) && ((xi >= 4) != (xj >= 4))) v = -1e30f;
    if ((wtype & 2) && ((yi >= 4) != (yj >= 4))) v = -1e30f;
  }
  biasT[id] = v;
}

// ---------------- K1: QKV GEMM, bf16 MFMA, counted-vmcnt pipeline (R8) ----------------
__global__ __launch_bounds__(256) void k_qkv_mfma(
    const __hip_bfloat16* __restrict__ xb, const __hip_bfloat16* __restrict__ wbt,
    const int* __restrict__ lutw,
    __hip_bfloat16* __restrict__ qb, __hip_bfloat16* __restrict__ kb,
    __hip_bfloat16* __restrict__ vb) {
  __shared__ __align__(16) short As[2][128 * 64];
  __shared__ __align__(16) short Bs[2][128 * 64];
  const int tid = threadIdx.x;
  const int lid = blockIdx.x;                 // 9408 blocks
  const int wid = (lid & 7) * 1176 + (lid >> 3);
  const int t0 = (wid / 12) * 128;
  const int n0 = (wid % 12) * 128;
  const int lane = tid & 63, wave = tid >> 6;
  const int wm = wave >> 1, wn = wave & 1;

  const __hip_bfloat16* asrc[4];
  const __hip_bfloat16* bsrc[4];
#pragma unroll
  for (int s = 0; s < 4; ++s) {
    int c = s * 256 + tid;
    int row = c >> 3, kc = c & 7;
    asrc[s] = xb + (size_t)(t0 + row) * 512 + kc * 8;
    bsrc[s] = wbt + (size_t)(n0 + row) * 512 + kc * 8;
  }

  f32x4 acc[4][4] = {};
  const int arow = wm * 64 + (lane & 15);
  const int brow = wn * 64 + (lane & 15);
  const int koff = (lane >> 4) * 8;
  const int sw = (lane & 7) << 3;

  // prologue: stage K-tile 0 into buf 0 (8 loads/thread)
#pragma unroll
  for (int s = 0; s < 4; ++s) {
    gload_lds16(asrc[s], (char*)As[0] + wave * 1024 + s * 4096);
    gload_lds16(bsrc[s], (char*)Bs[0] + wave * 1024 + s * 4096);
  }

  for (int t = 0; t < 8; ++t) {
    const int buf = t & 1;
    if (t < 7) {
      const int kt = (t + 1) * 64;
#pragma unroll
      for (int s = 0; s < 4; ++s) {
        gload_lds16(asrc[s] + kt, (char*)As[buf ^ 1] + wave * 1024 + s * 4096);
        gload_lds16(bsrc[s] + kt, (char*)Bs[buf ^ 1] + wave * 1024 + s * 4096);
      }
      asm volatile("s_waitcnt vmcnt(8)" ::: "memory");
    } else {
      asm volatile("s_waitcnt vmcnt(0)" ::: "memory");
    }
    __builtin_amdgcn_s_barrier();
    __builtin_amdgcn_sched_barrier(0);

    bf16x8 af[2][4], bfr[2][4];
#pragma unroll
    for (int kk = 0; kk < 2; ++kk) {
      const int eo = (kk * 32 + koff) ^ sw;
#pragma unroll
      for (int mf = 0; mf < 4; ++mf)
        af[kk][mf] = *(const bf16x8*)&As[buf][(arow + mf * 16) * 64 + eo];
#pragma unroll
      for (int nf = 0; nf < 4; ++nf)
        bfr[kk][nf] = *(const bf16x8*)&Bs[buf][(brow + nf * 16) * 64 + eo];
    }
    __builtin_amdgcn_s_setprio(1);
#pragma unroll
    for (int kk = 0; kk < 2; ++kk)
#pragma unroll
      for (int mf = 0; mf < 4; ++mf)
#pragma unroll
        for (int nf = 0; nf < 4; ++nf)
          acc[mf][nf] = __builtin_amdgcn_mfma_f32_16x16x32_bf16(
              af[kk][mf], bfr[kk][nf], acc[mf][nf], 0, 0, 0);
    __builtin_amdgcn_s_setprio(0);
    __builtin_amdgcn_s_barrier();
    __builtin_amdgcn_sched_barrier(0);
  }

  // epilogue: q/k/v -> windowed [b][h][win][pos49][d32]; offsets via LUT
  __hip_bfloat16* obs[4];
#pragma unroll
  for (int nf = 0; nf < 4; ++nf) {
    int n = n0 + wn * 64 + nf * 16 + (lane & 15);
    int sp = n >> 9, hc = n & 511, h = hc >> 5, d = hc & 31;
    obs[nf] = (sp == 0 ? qb : (sp == 1 ? kb : vb)) + (size_t)h * HEAD_STRIDE + d;
  }
  const int tbase = t0 + wm * 64 + (lane >> 4) * 4;
  int woff[4][4];
#pragma unroll
  for (int mf = 0; mf < 4; ++mf)
#pragma unroll
    for (int r = 0; r < 4; ++r)
      woff[mf][r] = lutw[tbase + mf * 16 + r];
#pragma unroll
  for (int mf = 0; mf < 4; ++mf)
#pragma unroll
    for (int r = 0; r < 4; ++r) {
      size_t off = (size_t)woff[mf][r];
#pragma unroll
      for (int nf = 0; nf < 4; ++nf)
        obs[nf][off] = __float2bfloat16(acc[mf][nf][r]);
    }
}

// ---------------- K2: attention via MFMA, one wave per (b,h,win) ----------------
// V fragments gathered directly from global (no LDS); P packed b32 into LDS.
__global__ __launch_bounds__(256) void k_attn_mfma(
    const __hip_bfloat16* __restrict__ qb, const __hip_bfloat16* __restrict__ kb,
    const __hip_bfloat16* __restrict__ vb, const float* __restrict__ biasT,
    __hip_bfloat16* __restrict__ ab) {
  __shared__ __align__(16) __hip_bfloat16 P[4][64 * 72];   // per-wave P[query][key]
  const int tid = threadIdx.x, lane = tid & 63, wave = tid >> 6;
  const int gid = blockIdx.x * 4 + wave;                   // (b*16+h)*64 + win
  const int win = gid & 63, h = (gid >> 6) & 15;
  const int wtype = (((win >> 3) == 7) ? 1 : 0) | (((win & 7) == 7) ? 2 : 0);
  const size_t qkbase = (size_t)gid * WIN_ELEMS;
  const int fr = lane & 15, fo = (lane >> 4) * 8;

  // V fragments direct from global, hoisted early to hide latency.
  // vf[kk][n2][j] = V[key = kk*32 + (lane>>4)*8 + j][d = n2*16 + fr]
  bf16x8 vfr[2][2];
  const short* vbs = (const short*)(vb + qkbase);
#pragma unroll
  for (int kk = 0; kk < 2; ++kk)
#pragma unroll
    for (int n2 = 0; n2 < 2; ++n2) {
      const short* vp = vbs + (kk * 32 + fo) * 32 + n2 * 16 + fr;
#pragma unroll
      for (int j = 0; j < 8; ++j) vfr[kk][n2][j] = vp[j * 32];
    }

  // Q,K fragments straight from global ([tok][d32], d==K of MFMA)
  bf16x8 kf[4], qf[4];
#pragma unroll
  for (int f = 0; f < 4; ++f) {
    kf[f] = *(const bf16x8*)(kb + qkbase + (size_t)(f * 16 + fr) * 32 + fo);
    qf[f] = *(const bf16x8*)(qb + qkbase + (size_t)(f * 16 + fr) * 32 + fo);
  }

  // S^T[key][query] = K @ Q^T
  f32x4 sacc[4][4] = {};   // [key-frag mf][query-frag nf]
  __builtin_amdgcn_s_setprio(1);
#pragma unroll
  for (int mf = 0; mf < 4; ++mf)
#pragma unroll
    for (int nf = 0; nf < 4; ++nf)
      sacc[mf][nf] = __builtin_amdgcn_mfma_f32_16x16x32_bf16(
          kf[mf], qf[nf], sacc[mf][nf], 0, 0, 0);
  __builtin_amdgcn_s_setprio(0);

  // scale + bias/mask table (fragment-layout, coalesced float4)
  const float* bp = biasT + (size_t)(wtype * 16 + h) * 4096;
#pragma unroll
  for (int mf = 0; mf < 4; ++mf)
#pragma unroll
    for (int r = 0; r < 4; ++r) {
      float4 bv = *(const float4*)(bp + ((mf * 4 + r) * 64 + lane) * 4);
      sacc[mf][0][r] = fmaf(sacc[mf][0][r], SCALE, bv.x);
      sacc[mf][1][r] = fmaf(sacc[mf][1][r], SCALE, bv.y);
      sacc[mf][2][r] = fmaf(sacc[mf][2][r], SCALE, bv.z);
      sacc[mf][3][r] = fmaf(sacc[mf][3][r], SCALE, bv.w);
    }

  // softmax over keys (rows of S^T): per query col, 16 local + 2 shuffles
  float inv[4];
#pragma unroll
  for (int nf = 0; nf < 4; ++nf) {
    float m = sacc[0][nf][0];
#pragma unroll
    for (int mf = 0; mf < 4; ++mf)
#pragma unroll
      for (int r = 0; r < 4; ++r) m = fmaxf(m, sacc[mf][nf][r]);
    m = fmaxf(m, __shfl_xor(m, 16));
    m = fmaxf(m, __shfl_xor(m, 32));
    float sum = 0.f;
#pragma unroll
    for (int mf = 0; mf < 4; ++mf)
#pragma unroll
      for (int r = 0; r < 4; ++r) {
        float e = __expf(sacc[mf][nf][r] - m);
        sacc[mf][nf][r] = e;
        sum += e;
      }
    sum += __shfl_xor(sum, 16);
    sum += __shfl_xor(sum, 32);
    inv[nf] = 1.0f / sum;
  }

  // write P[query][key] (bf16, key-pairs packed to b32), transposed for PV A-op
  __hip_bfloat16* pw = P[wave];
#pragma unroll
  for (int mf = 0; mf < 4; ++mf)
#pragma unroll
    for (int r = 0; r < 4; r += 2) {
      int key = mf * 16 + (lane >> 4) * 4 + r;
#pragma unroll
      for (int nf = 0; nf < 4; ++nf) {
        int query = nf * 16 + fr;
        *(unsigned*)&pw[query * 72 + key] =
            pack_bf2(sacc[mf][nf][r] * inv[nf], sacc[mf][nf][r + 1] * inv[nf]);
      }
    }

  // O = P @ V via MFMA; V from pre-gathered registers
  f32x4 oacc[4][2] = {};
#pragma unroll
  for (int kk = 0; kk < 2; ++kk) {
    __builtin_amdgcn_s_setprio(1);
#pragma unroll
    for (int mf = 0; mf < 4; ++mf) {
      bf16x8 pa = *(const bf16x8*)&pw[(mf * 16 + fr) * 72 + kk * 32 + fo];
#pragma unroll
      for (int n2 = 0; n2 < 2; ++n2)
        oacc[mf][n2] = __builtin_amdgcn_mfma_f32_16x16x32_bf16(
            pa, vfr[kk][n2], oacc[mf][n2], 0, 0, 0);
    }
    __builtin_amdgcn_s_setprio(0);
  }

  // store O rows < 49 to windowed [tok49][d32]
#pragma unroll
  for (int mf = 0; mf < 4; ++mf)
#pragma unroll
    for (int r = 0; r < 4; ++r) {
      int row = mf * 16 + (lane >> 4) * 4 + r;
      if (row < 49) {
#pragma unroll
        for (int n2 = 0; n2 < 2; ++n2)
          ab[qkbase + (size_t)row * 32 + n2 * 16 + fr] =
              __float2bfloat16(oacc[mf][n2][r]);
      }
    }
}

// ---------------- K3: output GEMM, bf16 MFMA, counted-vmcnt pipeline (R8) ----------------
__global__ __launch_bounds__(256) void k_out_mfma(
    const __hip_bfloat16* __restrict__ ab, const __hip_bfloat16* __restrict__ wot,
    const int* __restrict__ lutw, const int* __restrict__ luto,
    const float* __restrict__ bias, float* __restrict__ out) {
  __shared__ __align__(16) short As[2][128 * 64];
  __shared__ __align__(16) short Bs[2][128 * 64];
  const int tid = threadIdx.x;
  const int lid = blockIdx.x;                 // 3136 blocks
  const int wid = (lid & 7) * 392 + (lid >> 3);
  const int t0 = (wid >> 2) * 128;
  const int n0 = (wid & 3) * 128;
  const int lane = tid & 63, wave = tid >> 6;
  const int wm = wave >> 1, wn = wave & 1;

  size_t aoff[4];
  const __hip_bfloat16* bsrc[4];
#pragma unroll
  for (int s = 0; s < 4; ++s) {
    int c = s * 256 + tid;
    int row = c >> 3, kc = c & 7;
    aoff[s] = (size_t)lutw[t0 + row] + (size_t)(kc >> 2) * HEAD_STRIDE + (kc & 3) * 8;
    bsrc[s] = wot + (size_t)(n0 + row) * 512 + kc * 8;
  }

  f32x4 acc[4][4] = {};
  const int arow = wm * 64 + (lane & 15);
  const int brow = wn * 64 + (lane & 15);
  const int koff = (lane >> 4) * 8;
  const int sw = (lane & 7) << 3;

  // prologue: stage K-tile 0 into buf 0
#pragma unroll
  for (int s = 0; s < 4; ++s) {
    gload_lds16(ab + aoff[s], (char*)As[0] + wave * 1024 + s * 4096);
    gload_lds16(bsrc[s], (char*)Bs[0] + wave * 1024 + s * 4096);
  }

  for (int t = 0; t < 8; ++t) {
    const int buf = t & 1;
    if (t < 7) {
      const int kt = (t + 1) * 64;
      size_t hoff = (size_t)(kt >> 5) * HEAD_STRIDE;
#pragma unroll
      for (int s = 0; s < 4; ++s) {
        gload_lds16(ab + aoff[s] + hoff, (char*)As[buf ^ 1] + wave * 1024 + s * 4096);
        gload_lds16(bsrc[s] + kt, (char*)Bs[buf ^ 1] + wave * 1024 + s * 4096);
      }
      asm volatile("s_waitcnt vmcnt(8)" ::: "memory");
    } else {
      asm volatile("s_waitcnt vmcnt(0)" ::: "memory");
    }
    __builtin_amdgcn_s_barrier();
    __builtin_amdgcn_sched_barrier(0);

    bf16x8 af[2][4], bfr[2][4];
#pragma unroll
    for (int kk = 0; kk < 2; ++kk) {
      const int eo = kk * 32 + koff;
#pragma unroll
      for (int mf = 0; mf < 4; ++mf)
        af[kk][mf] = *(const bf16x8*)&As[buf][(arow + mf * 16) * 64 + eo];
#pragma unroll
      for (int nf = 0; nf < 4; ++nf)
        bfr[kk][nf] = *(const bf16x8*)&Bs[buf][(brow + nf * 16) * 64 + (eo ^ sw)];
    }
    __builtin_amdgcn_s_setprio(1);
#pragma unroll
    for (int kk = 0; kk < 2; ++kk)
#pragma unroll
      for (int mf = 0; mf < 4; ++mf)
#pragma unroll
        for (int nf = 0; nf < 4; ++nf)
          acc[mf][nf] = __builtin_amdgcn_mfma_f32_16x16x32_bf16(
              af[kk][mf], bfr[kk][nf], acc[mf][nf], 0, 0, 0);
    __builtin_amdgcn_s_setprio(0);
    __builtin_amdgcn_s_barrier();
    __builtin_amdgcn_sched_barrier(0);
  }

  float bia[4];
#pragma unroll
  for (int nf = 0; nf < 4; ++nf)
    bia[nf] = bias[n0 + wn * 64 + nf * 16 + (lane & 15)];

  const int tbase = t0 + wm * 64 + (lane >> 4) * 4;
  int ooff[4][4];
#pragma unroll
  for (int mf = 0; mf < 4; ++mf)
#pragma unroll
    for (int r = 0; r < 4; ++r)
      ooff[mf][r] = luto[tbase + mf * 16 + r];
#pragma unroll
  for (int mf = 0; mf < 4; ++mf) {
#pragma unroll
    for (int r = 0; r < 4; ++r) {
      float* op = out + (size_t)ooff[mf][r] + n0 + wn * 64 + (lane & 15);
#pragma unroll
      for (int nf = 0; nf < 4; ++nf) op[nf * 16] = acc[mf][nf][r] + bia[nf];
    }
  }
}

extern "C" void kernel_launch(void* const* d_in, const int* in_sizes, int n_in,
                              void* d_out, int out_size, void* d_ws, size_t ws_size,
                              hipStream_t stream) {
  const float* x     = (const float*)d_in[0];
  const float* w_qkv = (const float*)d_in[1];
  const float* pe    = (const float*)d_in[2];
  const float* w_out = (const float*)d_in[3];
  const float* b_out = (const float*)d_in[4];
  float* out = (float*)d_out;

  __hip_bfloat16* qb  = (__hip_bfloat16*)d_ws;          // 51,380,224
  __hip_bfloat16* kb  = qb + (size_t)QKV_ELEMS;         // 51,380,224
  __hip_bfloat16* vb  = kb + (size_t)QKV_ELEMS;         // 51,380,224
  __hip_bfloat16* xb  = vb + (size_t)QKV_ELEMS;         // 51,380,224 (aliased ab)
  __hip_bfloat16* ab  = xb;
  __hip_bfloat16* wbt = xb + (size_t)QKV_ELEMS;         // 786,432
  __hip_bfloat16* wot = wbt + (size_t)(1536 * 512);     // 262,144
  float* biasT = (float*)(wot + (size_t)(512 * 512));   // 262,144 f32 (1 MB)
  int* lutw = (int*)(biasT + 262144);                   // 100,352 int
  int* luto = lutw + NTOKENS;                           // 100,352 int

  k_prep_lut<<<dim3(392), dim3(256), 0, stream>>>(lutw, luto);
  k_prep_x<<<dim3(25088), dim3(256), 0, stream>>>(x, xb);
  k_transpose<<<dim3(24, 8), dim3(256), 0, stream>>>(w_qkv, wbt, 512, 1536);
  k_transpose<<<dim3(8, 8), dim3(256), 0, stream>>>(w_out, wot, 512, 512);
  k_prep_bias<<<dim3(1024), dim3(256), 0, stream>>>(pe, biasT);
  k_qkv_mfma<<<dim3(9408), dim3(256), 0, stream>>>(xb, wbt, lutw, qb, kb, vb);
  k_attn_mfma<<<dim3(8192), dim3(256), 0, stream>>>(qb, kb, vb, biasT, ab);
  k_out_mfma<<<dim3(3136), dim3(256), 0, stream>>>(ab, wot, lutw, luto, b_out, out);
}